// Round 10
// baseline (988.062 us; speedup 1.0000x reference)
//
#include <hip/hip_runtime.h>
#include <math.h>

#define NN 100000
#define NE 1000000
#define DH 64
#define DIN 128
#define DOUT 40
#define NL 7
#define SCAN_B 1024
#define NBLK ((NN + SCAN_B - 1) / SCAN_B)  // 98
#define NGRP (NN / 16)     // 6250 16-node groups (exact)
#define LBLK ((NGRP + 3) / 4)
#define COLB_CAP (NE + 16 * NN + 64)  // padded CSR capacity (entries)

typedef _Float16 v8h __attribute__((ext_vector_type(8)));
typedef _Float16 v2h __attribute__((ext_vector_type(2)));
typedef float v4f __attribute__((ext_vector_type(4)));

__device__ __forceinline__ float lane_bcast(float v, int l) {
  return __int_as_float(__builtin_amdgcn_readlane(__float_as_int(v), l));
}

// ---------------- CSR build ----------------
__global__ __launch_bounds__(256) void k_count(const int* __restrict__ dst,
                                               int* __restrict__ cnt) {
  int i = blockIdx.x * 256 + threadIdx.x;
  if (i < NE) atomicAdd(&cnt[dst[i]], 1);
}

// exclusive scan over PADDED counts: ceil16(cnt[i])
__global__ __launch_bounds__(SCAN_B) void k_scan1(const int* __restrict__ cnt,
                                                  int* __restrict__ rp16,
                                                  int* __restrict__ bsum) {
  __shared__ int buf[SCAN_B];
  int i = blockIdx.x * SCAN_B + threadIdx.x;
  int v = (i < NN) ? ((cnt[i] + 15) & ~15) : 0;
  buf[threadIdx.x] = v;
  __syncthreads();
  for (int off = 1; off < SCAN_B; off <<= 1) {
    int t = (threadIdx.x >= off) ? buf[threadIdx.x - off] : 0;
    __syncthreads();
    buf[threadIdx.x] += t;
    __syncthreads();
  }
  if (i < NN) rp16[i] = buf[threadIdx.x] - v;
  if (threadIdx.x == SCAN_B - 1) bsum[blockIdx.x] = buf[SCAN_B - 1];
}

__global__ __launch_bounds__(128) void k_scan2(int* __restrict__ bsum) {
  __shared__ int buf[128];
  int v = (threadIdx.x < NBLK) ? bsum[threadIdx.x] : 0;
  buf[threadIdx.x] = v;
  __syncthreads();
  for (int off = 1; off < 128; off <<= 1) {
    int t = (threadIdx.x >= off) ? buf[threadIdx.x - off] : 0;
    __syncthreads();
    buf[threadIdx.x] += t;
    __syncthreads();
  }
  if (threadIdx.x < NBLK) bsum[threadIdx.x] = buf[threadIdx.x] - v;
}

__global__ __launch_bounds__(SCAN_B) void k_scan3(int* __restrict__ rp16,
                                                  int* __restrict__ cur,
                                                  const int* __restrict__ bsum) {
  int i = blockIdx.x * SCAN_B + threadIdx.x;
  if (i < NN) {
    int rp = rp16[i] + bsum[blockIdx.x];
    rp16[i] = rp;
    cur[i] = rp;
  }
}

// colb stores BYTE offsets into the f16 msg array: src * DH * 2
__global__ __launch_bounds__(256) void k_scatter(const int* __restrict__ src,
                                                 const int* __restrict__ dst,
                                                 int* __restrict__ cur,
                                                 int* __restrict__ colb) {
  int i = blockIdx.x * 256 + threadIdx.x;
  if (i < NE) {
    int d = dst[i];
    int p = atomicAdd(&cur[d], 1);
    colb[p] = src[i] * (DH * 2);
  }
}

// ---------------- Encoder: h = x @ W_enc + b_enc ----------------
__global__ __launch_bounds__(256) void k_encoder(const float* __restrict__ x,
                                                 const float* __restrict__ W,
                                                 const float* __restrict__ b,
                                                 float* __restrict__ h) {
  int lane = threadIdx.x & 63;
  float wc[DIN];
#pragma unroll
  for (int k = 0; k < DIN; ++k) wc[k] = W[k * DH + lane];
  float bj = b[lane];
  int wid = (blockIdx.x * blockDim.x + threadIdx.x) >> 6;
  int nw = (gridDim.x * blockDim.x) >> 6;
  for (int n = wid; n < NN; n += nw) {
    float v0 = x[n * DIN + lane];
    float v1 = x[n * DIN + 64 + lane];
    float acc = bj;
#pragma unroll
    for (int k = 0; k < 64; ++k) acc = fmaf(lane_bcast(v0, k), wc[k], acc);
#pragma unroll
    for (int k = 0; k < 64; ++k) acc = fmaf(lane_bcast(v1, k), wc[64 + k], acc);
    h[n * DH + lane] = acc;
  }
}

// ---------------- Message precompute: msg = f16(relu(bn(h)) + eps) ----------------
__global__ __launch_bounds__(256) void k_msg(const float* __restrict__ h,
                                             const float* __restrict__ stats_in,
                                             const float* __restrict__ gamma,
                                             const float* __restrict__ beta,
                                             _Float16* __restrict__ msg) {
  int lane = threadIdx.x & 63;
  float scale = 1.f, shift = 0.f;
  if (stats_in) {
    float mu = stats_in[lane] * (1.0f / NN);
    float var = stats_in[64 + lane] * (1.0f / NN) - mu * mu;
    scale = gamma[lane] * rsqrtf(var + 1e-5f);
    shift = beta[lane] - mu * scale;
  }
  int wid = (blockIdx.x * blockDim.x + threadIdx.x) >> 6;
  int nw = (gridDim.x * blockDim.x) >> 6;
  for (int n = wid; n < NN; n += nw) {
    float r = h[n * DH + lane];
    float v = fmaxf(fmaf(r, scale, shift), 0.f) + 1e-7f;
    msg[n * DH + lane] = (_Float16)v;
  }
}

// ---------------- Gather + segment softmax agg: one wave per node ----------------
// lane = (e = edge octet 0..7, c = feature octet 0..7). 16 padded edges/round:
// 2x dword col loads + 2x dwordx4 gathers (16B/lane, 8 edges x 8 feats each).
__global__ __launch_bounds__(256, 8) void k_agg(const _Float16* __restrict__ msg,
                                                const int* __restrict__ rp16,
                                                const int* __restrict__ cnt,
                                                const int* __restrict__ colb,
                                                _Float16* __restrict__ agg) {
  const int lane = threadIdx.x & 63;
  const int e = lane >> 3;  // edge sub-index within octet
  const int c = lane & 7;   // feature octet (features 8c..8c+7)
  const int n = (blockIdx.x * 256 + threadIdx.x) >> 6;  // wave-uniform node
  const int beg = rp16[n];  // %16 == 0
  const int deg = cnt[n];
  const char* mb = (const char*)msg + 16 * c;
  float s[8], t[8];
#pragma unroll
  for (int q = 0; q < 8; ++q) { s[q] = 0.f; t[q] = 0.f; }
  for (int j = 0; j < deg; j += 16) {
    int off0 = colb[beg + j + e];       // edge j+e
    int off1 = colb[beg + j + 8 + e];   // edge j+8+e
    v8h g0 = *(const v8h*)(mb + off0);
    v8h g1 = *(const v8h*)(mb + off1);
    bool m0 = (j + e) < deg;            // per-lane tail mask (pads read row 0)
    bool m1 = (j + 8 + e) < deg;
#pragma unroll
    for (int q = 0; q < 8; ++q) {
      float v0 = (float)g0[q];
      float e0 = m0 ? __expf(v0) : 0.f;
      s[q] += e0;
      t[q] = fmaf(e0, v0, t[q]);
      float v1 = (float)g1[q];
      float e1 = m1 ? __expf(v1) : 0.f;
      s[q] += e1;
      t[q] = fmaf(e1, v1, t[q]);
    }
  }
  // reduce across the 8 edge-octets (lanes xor 8,16,32 share feature octet)
#pragma unroll
  for (int q = 0; q < 8; ++q) {
    s[q] += __shfl_xor(s[q], 8, 64);
    t[q] += __shfl_xor(t[q], 8, 64);
    s[q] += __shfl_xor(s[q], 16, 64);
    t[q] += __shfl_xor(t[q], 16, 64);
    s[q] += __shfl_xor(s[q], 32, 64);
    t[q] += __shfl_xor(t[q], 32, 64);
  }
  if (e == 0) {
    v8h r;
#pragma unroll
    for (int q = 0; q < 8; ++q) r[q] = (_Float16)(t[q] / (s[q] + 1e-16f));
    *(v8h*)((char*)agg + (size_t)n * 128 + 16 * c) = r;
  }
}

// ---------------- MFMA layer: combine(h,agg) -> GEMM (+bias,+res) -> col-stats
//                  One wave = 16 contiguous nodes. ----------------
__global__ __launch_bounds__(256) void k_mfma(
    const float* __restrict__ h_pre, const _Float16* __restrict__ agg,
    const float* __restrict__ stats_in,
    const float* __restrict__ gamma, const float* __restrict__ beta,
    const float* __restrict__ W, const float* __restrict__ b, int add_res,
    float* __restrict__ hout, float* __restrict__ stats_out) {
  __shared__ _Float16 Atile[4][1024];  // per-wave swizzled 16x64 f16 A-tile (8 KB)
  const int tid = threadIdx.x;
  const int w = tid >> 6, lane = tid & 63;
  const int gid = blockIdx.x * 4 + w;
  const int row = lane & 15, hi = lane >> 4;

  float ss0 = 0, ss1 = 0, ss2 = 0, ss3 = 0;
  float qq0 = 0, qq1 = 0, qq2 = 0, qq3 = 0;

  if (gid < NGRP) {  // wave-uniform
    float scale = 1.f, shift = 0.f;
    if (stats_in) {
      float mu = stats_in[lane] * (1.0f / NN);
      float var = stats_in[64 + lane] * (1.0f / NN) - mu * mu;
      scale = gamma[lane] * rsqrtf(var + 1e-5f);
      shift = beta[lane] - mu * scale;
    }
    // B fragments of W (64x64, row-major [k][n]) in f16:
    // lane holds k = kt*32 + hi*8 + j, n = ct*16 + row
    v8h bf[2][4];
#pragma unroll
    for (int kt = 0; kt < 2; ++kt)
#pragma unroll
      for (int ct = 0; ct < 4; ++ct)
#pragma unroll
        for (int j = 0; j < 8; ++j)
          bf[kt][ct][j] = (_Float16)W[(kt * 32 + hi * 8 + j) * DH + ct * 16 + row];

    const int base = gid * 16;
    const float* hl = h_pre + lane;
    const _Float16* agl = agg + lane;
    _Float16* At = &Atile[w][0];

#pragma unroll 4
    for (int i = 0; i < 16; ++i) {
      size_t o = (size_t)(base + i) * DH;
      float raw = hl[o];
      float ag = (float)agl[o];
      float v = stats_in ? fmaxf(fmaf(raw, scale, shift), 0.f) : raw;
      v += ag;
      // swizzled write: row i, feature lane (byte col 2*lane)
      At[(i * 128 + ((lane * 2) ^ ((i & 7) << 4))) >> 1] = (_Float16)v;
    }

    // A fragments: lane reads row=(lane&15), k = kt*32 + hi*8 + j (16B swizzle-stable)
    const int sw = (row & 7) << 4;
    v8h a0 = *(const v8h*)&At[((row * 128) + ((hi * 16) ^ sw)) >> 1];
    v8h a1 = *(const v8h*)&At[((row * 128) + ((64 + hi * 16) ^ sw)) >> 1];
    v4f c0 = {0, 0, 0, 0}, c1 = {0, 0, 0, 0}, c2 = {0, 0, 0, 0}, c3 = {0, 0, 0, 0};
    c0 = __builtin_amdgcn_mfma_f32_16x16x32_f16(a0, bf[0][0], c0, 0, 0, 0);
    c0 = __builtin_amdgcn_mfma_f32_16x16x32_f16(a1, bf[1][0], c0, 0, 0, 0);
    c1 = __builtin_amdgcn_mfma_f32_16x16x32_f16(a0, bf[0][1], c1, 0, 0, 0);
    c1 = __builtin_amdgcn_mfma_f32_16x16x32_f16(a1, bf[1][1], c1, 0, 0, 0);
    c2 = __builtin_amdgcn_mfma_f32_16x16x32_f16(a0, bf[0][2], c2, 0, 0, 0);
    c2 = __builtin_amdgcn_mfma_f32_16x16x32_f16(a1, bf[1][2], c2, 0, 0, 0);
    c3 = __builtin_amdgcn_mfma_f32_16x16x32_f16(a0, bf[0][3], c3, 0, 0, 0);
    c3 = __builtin_amdgcn_mfma_f32_16x16x32_f16(a1, bf[1][3], c3, 0, 0, 0);

    // epilogue in C layout: col = ct*16 + row, node = base + hi*4 + reg
    float b0 = b[row], b1 = b[16 + row], b2 = b[32 + row], b3 = b[48 + row];
#pragma unroll
    for (int reg = 0; reg < 4; ++reg) {
      size_t o = (size_t)(base + hi * 4 + reg) * DH;
      float a0v = c0[reg] + b0;
      float a1v = c1[reg] + b1;
      float a2v = c2[reg] + b2;
      float a3v = c3[reg] + b3;
      if (add_res) {
        a0v += h_pre[o + row];
        a1v += h_pre[o + 16 + row];
        a2v += h_pre[o + 32 + row];
        a3v += h_pre[o + 48 + row];
      }
      hout[o + row] = a0v;
      hout[o + 16 + row] = a1v;
      hout[o + 32 + row] = a2v;
      hout[o + 48 + row] = a3v;
      ss0 += a0v; qq0 = fmaf(a0v, a0v, qq0);
      ss1 += a1v; qq1 = fmaf(a1v, a1v, qq1);
      ss2 += a2v; qq2 = fmaf(a2v, a2v, qq2);
      ss3 += a3v; qq3 = fmaf(a3v, a3v, qq3);
    }
  }

  // reduce across the 4 row-groups (lanes l, l^16, l^32 share column)
#pragma unroll
  for (int off = 16; off <= 32; off <<= 1) {
    ss0 += __shfl_xor(ss0, off, 64); ss1 += __shfl_xor(ss1, off, 64);
    ss2 += __shfl_xor(ss2, off, 64); ss3 += __shfl_xor(ss3, off, 64);
    qq0 += __shfl_xor(qq0, off, 64); qq1 += __shfl_xor(qq1, off, 64);
    qq2 += __shfl_xor(qq2, off, 64); qq3 += __shfl_xor(qq3, off, 64);
  }
  __syncthreads();  // done with f16 A-tiles; reuse LDS as float scratch
  float* Sr = (float*)&Atile[0][0];
  if (lane < 16) {
    Sr[w * 128 + lane] = ss0;       Sr[w * 128 + 16 + lane] = ss1;
    Sr[w * 128 + 32 + lane] = ss2;  Sr[w * 128 + 48 + lane] = ss3;
    Sr[w * 128 + 64 + lane] = qq0;  Sr[w * 128 + 80 + lane] = qq1;
    Sr[w * 128 + 96 + lane] = qq2;  Sr[w * 128 + 112 + lane] = qq3;
  }
  __syncthreads();
  if (tid < 128) {
    float vsum = Sr[tid] + Sr[128 + tid] + Sr[256 + tid] + Sr[384 + tid];
    atomicAdd(&stats_out[tid], vsum);
  }
}

// ---------------- Final BN+ReLU + prediction head + log_softmax ----------------
__global__ __launch_bounds__(256) void k_pred(
    const float* __restrict__ h_pre, const float* __restrict__ stats_in,
    const float* __restrict__ gamma, const float* __restrict__ beta,
    const float* __restrict__ Wp, const float* __restrict__ bp,
    float* __restrict__ out) {
  int lane = threadIdx.x & 63;
  float mu = stats_in[lane] * (1.0f / NN);
  float var = stats_in[64 + lane] * (1.0f / NN) - mu * mu;
  float scale = gamma[lane] * rsqrtf(var + 1e-5f);
  float shift = beta[lane] - mu * scale;
  int lc = lane < DOUT ? lane : DOUT - 1;
  float wc[DH];
#pragma unroll
  for (int k = 0; k < DH; ++k) wc[k] = Wp[k * DOUT + lc];
  float bj = bp[lc];
  int wid = (blockIdx.x * blockDim.x + threadIdx.x) >> 6;
  int nw = (gridDim.x * blockDim.x) >> 6;
  for (int n = wid; n < NN; n += nw) {
    float raw = h_pre[n * DH + lane];
    float v = fmaxf(fmaf(raw, scale, shift), 0.f);
    float acc = bj;
#pragma unroll
    for (int k = 0; k < DH; ++k) acc = fmaf(lane_bcast(v, k), wc[k], acc);
    float xm = (lane < DOUT) ? acc : -INFINITY;
#pragma unroll
    for (int o = 32; o >= 1; o >>= 1) xm = fmaxf(xm, __shfl_xor(xm, o, 64));
    float e = (lane < DOUT) ? __expf(acc - xm) : 0.f;
#pragma unroll
    for (int o = 32; o >= 1; o >>= 1) e += __shfl_xor(e, o, 64);
    if (lane < DOUT) out[n * DOUT + lane] = acc - xm - __logf(e);
  }
}

extern "C" void kernel_launch(void* const* d_in, const int* in_sizes, int n_in,
                              void* d_out, int out_size, void* d_ws, size_t ws_size,
                              hipStream_t stream) {
  const float* x      = (const float*)d_in[0];
  const int*   ei     = (const int*)d_in[1];
  const float* W_enc  = (const float*)d_in[2];
  const float* b_enc  = (const float*)d_in[3];
  const float* Wg     = (const float*)d_in[4];
  const float* bg     = (const float*)d_in[5];
  const float* gamma  = (const float*)d_in[6];
  const float* beta   = (const float*)d_in[7];
  const float* W_pred = (const float*)d_in[8];
  const float* b_pred = (const float*)d_in[9];
  float* out = (float*)d_out;

  const int* src = ei;
  const int* dst = ei + NE;

  char* p = (char*)d_ws;
  auto alloc = [&](size_t bytes) -> void* {
    void* r = (void*)p;
    p += (bytes + 255) & ~(size_t)255;
    return r;
  };
  float*     hA      = (float*)alloc((size_t)NN * DH * 4);
  float*     hB      = (float*)alloc((size_t)NN * DH * 4);
  _Float16*  msg     = (_Float16*)alloc((size_t)NN * DH * 2);
  _Float16*  agg     = (_Float16*)alloc((size_t)NN * DH * 2);
  int*       rp16    = (int*)alloc((size_t)(NN + 1) * 4);
  int*       cur     = (int*)alloc((size_t)NN * 4);
  int*       cnt     = (int*)alloc((size_t)NN * 4);
  int*       colb    = (int*)alloc((size_t)COLB_CAP * 4);
  int*       bsum    = (int*)alloc((size_t)NBLK * 4);
  float*     stats   = (float*)alloc((size_t)NL * 128 * 4);

  hipMemsetAsync(cnt, 0, (size_t)NN * 4, stream);
  hipMemsetAsync(stats, 0, (size_t)NL * 128 * 4, stream);
  hipMemsetAsync(colb, 0, (size_t)COLB_CAP * 4, stream);  // pads -> row 0 (masked)

  // ---- CSR build (16-padded segments) ----
  k_count<<<(NE + 255) / 256, 256, 0, stream>>>(dst, cnt);
  k_scan1<<<NBLK, SCAN_B, 0, stream>>>(cnt, rp16, bsum);
  k_scan2<<<1, 128, 0, stream>>>(bsum);
  k_scan3<<<NBLK, SCAN_B, 0, stream>>>(rp16, cur, bsum);
  k_scatter<<<(NE + 255) / 256, 256, 0, stream>>>(src, dst, cur, colb);

  // ---- Encoder ----
  k_encoder<<<1024, 256, 0, stream>>>(x, W_enc, b_enc, hA);

  const int MSG_BLOCKS = 1024;
  const int AGG_BLOCKS = NN * 64 / 256;  // one wave per node

  // ---- Layer 0 (no BN; combine uses raw h; msg = relu(h)+eps) ----
  k_msg<<<MSG_BLOCKS, 256, 0, stream>>>(hA, nullptr, nullptr, nullptr, msg);
  k_agg<<<AGG_BLOCKS, 256, 0, stream>>>(msg, rp16, cnt, colb, agg);
  k_mfma<<<LBLK, 256, 0, stream>>>(
      hA, agg, nullptr, nullptr, nullptr, Wg, bg, 0, hB, stats);

  float* h = hB;
  float* hn = hA;
  for (int l = 1; l < NL; ++l) {
    const float* st = stats + (size_t)(l - 1) * 128;
    const float* g  = gamma + (size_t)(l - 1) * DH;
    const float* be = beta + (size_t)(l - 1) * DH;
    k_msg<<<MSG_BLOCKS, 256, 0, stream>>>(h, st, g, be, msg);
    k_agg<<<AGG_BLOCKS, 256, 0, stream>>>(msg, rp16, cnt, colb, agg);
    k_mfma<<<LBLK, 256, 0, stream>>>(
        h, agg, st, g, be,
        Wg + (size_t)l * DH * DH, bg + (size_t)l * DH, 1,
        hn, stats + (size_t)l * 128);
    float* tmp = h; h = hn; hn = tmp;
  }

  // ---- Final BN + ReLU + prediction + log_softmax ----
  k_pred<<<1024, 256, 0, stream>>>(
      h, stats + (size_t)(NL - 1) * 128,
      gamma + (size_t)(NL - 1) * DH, beta + (size_t)(NL - 1) * DH,
      W_pred, b_pred, out);
}

// Round 11
// 823.067 us; speedup vs baseline: 1.2005x; 1.2005x over previous
//
#include <hip/hip_runtime.h>
#include <math.h>

#define NN 100000
#define NE 1000000
#define DH 64
#define DIN 128
#define DOUT 40
#define NL 7
#define SCAN_B 1024
#define NBLK ((NN + SCAN_B - 1) / SCAN_B)  // 98
#define NGRP (NN / 16)     // 6250 16-node groups (exact)
#define LBLK ((NGRP + 3) / 4)
#define COLB_CAP (NE + 16 * NN + 64)  // padded CSR capacity (entries)

typedef _Float16 v8h __attribute__((ext_vector_type(8)));
typedef float v4f __attribute__((ext_vector_type(4)));

__device__ __forceinline__ float lane_bcast(float v, int l) {
  return __int_as_float(__builtin_amdgcn_readlane(__float_as_int(v), l));
}

// ---------------- CSR build (3-pass, slot-memo, no atomic in place pass) ----------------
__global__ __launch_bounds__(256) void k_count2(const int* __restrict__ dst,
                                                int* __restrict__ cnt,
                                                int* __restrict__ pi) {
  int i = blockIdx.x * 256 + threadIdx.x;
  if (i < NE) pi[i] = atomicAdd(&cnt[dst[i]], 1);
}

// exclusive scan over PADDED counts: ceil16(cnt[i])
__global__ __launch_bounds__(SCAN_B) void k_scan1(const int* __restrict__ cnt,
                                                  int* __restrict__ rp16,
                                                  int* __restrict__ bsum) {
  __shared__ int buf[SCAN_B];
  int i = blockIdx.x * SCAN_B + threadIdx.x;
  int v = (i < NN) ? ((cnt[i] + 15) & ~15) : 0;
  buf[threadIdx.x] = v;
  __syncthreads();
  for (int off = 1; off < SCAN_B; off <<= 1) {
    int t = (threadIdx.x >= off) ? buf[threadIdx.x - off] : 0;
    __syncthreads();
    buf[threadIdx.x] += t;
    __syncthreads();
  }
  if (i < NN) rp16[i] = buf[threadIdx.x] - v;
  if (threadIdx.x == SCAN_B - 1) bsum[blockIdx.x] = buf[SCAN_B - 1];
}

__global__ __launch_bounds__(128) void k_scan2(int* __restrict__ bsum) {
  __shared__ int buf[128];
  int v = (threadIdx.x < NBLK) ? bsum[threadIdx.x] : 0;
  buf[threadIdx.x] = v;
  __syncthreads();
  for (int off = 1; off < 128; off <<= 1) {
    int t = (threadIdx.x >= off) ? buf[threadIdx.x - off] : 0;
    __syncthreads();
    buf[threadIdx.x] += t;
    __syncthreads();
  }
  if (threadIdx.x < NBLK) bsum[threadIdx.x] = buf[threadIdx.x] - v;
}

__global__ __launch_bounds__(SCAN_B) void k_scan3(int* __restrict__ rp16,
                                                  const int* __restrict__ bsum) {
  int i = blockIdx.x * SCAN_B + threadIdx.x;
  if (i < NN) rp16[i] += bsum[blockIdx.x];
}

// place pass: no atomics — slot came from k_count2
// colb stores BYTE offsets into the f16 msg array: src * DH * 2
__global__ __launch_bounds__(256) void k_place(const int* __restrict__ src,
                                               const int* __restrict__ dst,
                                               const int* __restrict__ rp16,
                                               const int* __restrict__ pi,
                                               int* __restrict__ colb) {
  int i = blockIdx.x * 256 + threadIdx.x;
  if (i < NE) colb[rp16[dst[i]] + pi[i]] = src[i] * (DH * 2);
}

// ---------------- Encoder: h = x @ W_enc + b_enc ----------------
__global__ __launch_bounds__(256) void k_encoder(const float* __restrict__ x,
                                                 const float* __restrict__ W,
                                                 const float* __restrict__ b,
                                                 float* __restrict__ h) {
  int lane = threadIdx.x & 63;
  float wc[DIN];
#pragma unroll
  for (int k = 0; k < DIN; ++k) wc[k] = W[k * DH + lane];
  float bj = b[lane];
  int wid = (blockIdx.x * blockDim.x + threadIdx.x) >> 6;
  int nw = (gridDim.x * blockDim.x) >> 6;
  for (int n = wid; n < NN; n += nw) {
    float v0 = x[n * DIN + lane];
    float v1 = x[n * DIN + 64 + lane];
    float acc = bj;
#pragma unroll
    for (int k = 0; k < 64; ++k) acc = fmaf(lane_bcast(v0, k), wc[k], acc);
#pragma unroll
    for (int k = 0; k < 64; ++k) acc = fmaf(lane_bcast(v1, k), wc[64 + k], acc);
    h[n * DH + lane] = acc;
  }
}

// ---------------- Message precompute: msg = f16(relu(bn(h)) + eps) ----------------
__global__ __launch_bounds__(256) void k_msg(const float* __restrict__ h,
                                             const float* __restrict__ stats_in,
                                             const float* __restrict__ gamma,
                                             const float* __restrict__ beta,
                                             _Float16* __restrict__ msg) {
  int lane = threadIdx.x & 63;
  float scale = 1.f, shift = 0.f;
  if (stats_in) {
    float mu = stats_in[lane] * (1.0f / NN);
    float var = stats_in[64 + lane] * (1.0f / NN) - mu * mu;
    scale = gamma[lane] * rsqrtf(var + 1e-5f);
    shift = beta[lane] - mu * scale;
  }
  int wid = (blockIdx.x * blockDim.x + threadIdx.x) >> 6;
  int nw = (gridDim.x * blockDim.x) >> 6;
  for (int n = wid; n < NN; n += nw) {
    float r = h[n * DH + lane];
    float v = fmaxf(fmaf(r, scale, shift), 0.f) + 1e-7f;
    msg[n * DH + lane] = (_Float16)v;
  }
}

// ---------------- Gather + segment softmax agg: one wave per node ----------------
// R8-proven shape: one fully-coalesced 128B msg row per gather instruction
// (2B/lane x 64 lanes). Padded CSR: col loads unconditional, tail masked.
__global__ __launch_bounds__(256, 8) void k_agg(const _Float16* __restrict__ msg,
                                                const int* __restrict__ rp16,
                                                const int* __restrict__ cnt,
                                                const int* __restrict__ colb,
                                                _Float16* __restrict__ agg) {
  const int lane = threadIdx.x & 63;
  const int n = (blockIdx.x * 256 + threadIdx.x) >> 6;  // wave-uniform node
  const int beg = rp16[n];  // %16 == 0
  const int deg = cnt[n];
  const char* mb = (const char*)msg + 2 * lane;
  float s = 0.f, t = 0.f;
  for (int j = 0; j < deg; j += 16) {
    int cc[16];
#pragma unroll
    for (int k = 0; k < 16; ++k) cc[k] = colb[beg + j + k];  // padded: safe
    float vv[16];
#pragma unroll
    for (int k = 0; k < 16; ++k) vv[k] = (float)(*(const _Float16*)(mb + cc[k]));
    int rem = deg - j;  // wave-uniform
#pragma unroll
    for (int k = 0; k < 16; ++k) {
      float e = (k < rem) ? __expf(vv[k]) : 0.f;
      s += e;
      t = fmaf(e, vv[k], t);
    }
  }
  agg[(size_t)n * DH + lane] = (_Float16)(t / (s + 1e-16f));
}

// ---------------- MFMA layer: combine(h,agg) -> GEMM (+bias,+res) -> col-stats
//                  One wave = 16 contiguous nodes. ----------------
__global__ __launch_bounds__(256) void k_mfma(
    const float* __restrict__ h_pre, const _Float16* __restrict__ agg,
    const float* __restrict__ stats_in,
    const float* __restrict__ gamma, const float* __restrict__ beta,
    const float* __restrict__ W, const float* __restrict__ b, int add_res,
    float* __restrict__ hout, float* __restrict__ stats_out) {
  __shared__ _Float16 Atile[4][1024];  // per-wave swizzled 16x64 f16 A-tile (8 KB)
  const int tid = threadIdx.x;
  const int w = tid >> 6, lane = tid & 63;
  const int gid = blockIdx.x * 4 + w;
  const int row = lane & 15, hi = lane >> 4;

  float ss0 = 0, ss1 = 0, ss2 = 0, ss3 = 0;
  float qq0 = 0, qq1 = 0, qq2 = 0, qq3 = 0;

  if (gid < NGRP) {  // wave-uniform
    float scale = 1.f, shift = 0.f;
    if (stats_in) {
      float mu = stats_in[lane] * (1.0f / NN);
      float var = stats_in[64 + lane] * (1.0f / NN) - mu * mu;
      scale = gamma[lane] * rsqrtf(var + 1e-5f);
      shift = beta[lane] - mu * scale;
    }
    // B fragments of W (64x64, row-major [k][n]) in f16:
    // lane holds k = kt*32 + hi*8 + j, n = ct*16 + row
    v8h bf[2][4];
#pragma unroll
    for (int kt = 0; kt < 2; ++kt)
#pragma unroll
      for (int ct = 0; ct < 4; ++ct)
#pragma unroll
        for (int j = 0; j < 8; ++j)
          bf[kt][ct][j] = (_Float16)W[(kt * 32 + hi * 8 + j) * DH + ct * 16 + row];

    const int base = gid * 16;
    const float* hl = h_pre + lane;
    const _Float16* agl = agg + lane;
    _Float16* At = &Atile[w][0];

#pragma unroll 4
    for (int i = 0; i < 16; ++i) {
      size_t o = (size_t)(base + i) * DH;
      float raw = hl[o];
      float ag = (float)agl[o];
      float v = stats_in ? fmaxf(fmaf(raw, scale, shift), 0.f) : raw;
      v += ag;
      // swizzled write: row i, feature lane (byte col 2*lane)
      At[(i * 128 + ((lane * 2) ^ ((i & 7) << 4))) >> 1] = (_Float16)v;
    }

    // A fragments: lane reads row=(lane&15), k = kt*32 + hi*8 + j (16B swizzle-stable)
    const int sw = (row & 7) << 4;
    v8h a0 = *(const v8h*)&At[((row * 128) + ((hi * 16) ^ sw)) >> 1];
    v8h a1 = *(const v8h*)&At[((row * 128) + ((64 + hi * 16) ^ sw)) >> 1];
    v4f c0 = {0, 0, 0, 0}, c1 = {0, 0, 0, 0}, c2 = {0, 0, 0, 0}, c3 = {0, 0, 0, 0};
    c0 = __builtin_amdgcn_mfma_f32_16x16x32_f16(a0, bf[0][0], c0, 0, 0, 0);
    c0 = __builtin_amdgcn_mfma_f32_16x16x32_f16(a1, bf[1][0], c0, 0, 0, 0);
    c1 = __builtin_amdgcn_mfma_f32_16x16x32_f16(a0, bf[0][1], c1, 0, 0, 0);
    c1 = __builtin_amdgcn_mfma_f32_16x16x32_f16(a1, bf[1][1], c1, 0, 0, 0);
    c2 = __builtin_amdgcn_mfma_f32_16x16x32_f16(a0, bf[0][2], c2, 0, 0, 0);
    c2 = __builtin_amdgcn_mfma_f32_16x16x32_f16(a1, bf[1][2], c2, 0, 0, 0);
    c3 = __builtin_amdgcn_mfma_f32_16x16x32_f16(a0, bf[0][3], c3, 0, 0, 0);
    c3 = __builtin_amdgcn_mfma_f32_16x16x32_f16(a1, bf[1][3], c3, 0, 0, 0);

    // epilogue in C layout: col = ct*16 + row, node = base + hi*4 + reg
    float b0 = b[row], b1 = b[16 + row], b2 = b[32 + row], b3 = b[48 + row];
#pragma unroll
    for (int reg = 0; reg < 4; ++reg) {
      size_t o = (size_t)(base + hi * 4 + reg) * DH;
      float a0v = c0[reg] + b0;
      float a1v = c1[reg] + b1;
      float a2v = c2[reg] + b2;
      float a3v = c3[reg] + b3;
      if (add_res) {
        a0v += h_pre[o + row];
        a1v += h_pre[o + 16 + row];
        a2v += h_pre[o + 32 + row];
        a3v += h_pre[o + 48 + row];
      }
      hout[o + row] = a0v;
      hout[o + 16 + row] = a1v;
      hout[o + 32 + row] = a2v;
      hout[o + 48 + row] = a3v;
      ss0 += a0v; qq0 = fmaf(a0v, a0v, qq0);
      ss1 += a1v; qq1 = fmaf(a1v, a1v, qq1);
      ss2 += a2v; qq2 = fmaf(a2v, a2v, qq2);
      ss3 += a3v; qq3 = fmaf(a3v, a3v, qq3);
    }
  }

  // reduce across the 4 row-groups (lanes l, l^16, l^32 share column)
#pragma unroll
  for (int off = 16; off <= 32; off <<= 1) {
    ss0 += __shfl_xor(ss0, off, 64); ss1 += __shfl_xor(ss1, off, 64);
    ss2 += __shfl_xor(ss2, off, 64); ss3 += __shfl_xor(ss3, off, 64);
    qq0 += __shfl_xor(qq0, off, 64); qq1 += __shfl_xor(qq1, off, 64);
    qq2 += __shfl_xor(qq2, off, 64); qq3 += __shfl_xor(qq3, off, 64);
  }
  __syncthreads();  // done with f16 A-tiles; reuse LDS as float scratch
  float* Sr = (float*)&Atile[0][0];
  if (lane < 16) {
    Sr[w * 128 + lane] = ss0;       Sr[w * 128 + 16 + lane] = ss1;
    Sr[w * 128 + 32 + lane] = ss2;  Sr[w * 128 + 48 + lane] = ss3;
    Sr[w * 128 + 64 + lane] = qq0;  Sr[w * 128 + 80 + lane] = qq1;
    Sr[w * 128 + 96 + lane] = qq2;  Sr[w * 128 + 112 + lane] = qq3;
  }
  __syncthreads();
  if (tid < 128) {
    float vsum = Sr[tid] + Sr[128 + tid] + Sr[256 + tid] + Sr[384 + tid];
    atomicAdd(&stats_out[tid], vsum);
  }
}

// ---------------- Final BN+ReLU + prediction head + log_softmax ----------------
__global__ __launch_bounds__(256) void k_pred(
    const float* __restrict__ h_pre, const float* __restrict__ stats_in,
    const float* __restrict__ gamma, const float* __restrict__ beta,
    const float* __restrict__ Wp, const float* __restrict__ bp,
    float* __restrict__ out) {
  int lane = threadIdx.x & 63;
  float mu = stats_in[lane] * (1.0f / NN);
  float var = stats_in[64 + lane] * (1.0f / NN) - mu * mu;
  float scale = gamma[lane] * rsqrtf(var + 1e-5f);
  float shift = beta[lane] - mu * scale;
  int lc = lane < DOUT ? lane : DOUT - 1;
  float wc[DH];
#pragma unroll
  for (int k = 0; k < DH; ++k) wc[k] = Wp[k * DOUT + lc];
  float bj = bp[lc];
  int wid = (blockIdx.x * blockDim.x + threadIdx.x) >> 6;
  int nw = (gridDim.x * blockDim.x) >> 6;
  for (int n = wid; n < NN; n += nw) {
    float raw = h_pre[n * DH + lane];
    float v = fmaxf(fmaf(raw, scale, shift), 0.f);
    float acc = bj;
#pragma unroll
    for (int k = 0; k < DH; ++k) acc = fmaf(lane_bcast(v, k), wc[k], acc);
    float xm = (lane < DOUT) ? acc : -INFINITY;
#pragma unroll
    for (int o = 32; o >= 1; o >>= 1) xm = fmaxf(xm, __shfl_xor(xm, o, 64));
    float e = (lane < DOUT) ? __expf(acc - xm) : 0.f;
#pragma unroll
    for (int o = 32; o >= 1; o >>= 1) e += __shfl_xor(e, o, 64);
    if (lane < DOUT) out[n * DOUT + lane] = acc - xm - __logf(e);
  }
}

extern "C" void kernel_launch(void* const* d_in, const int* in_sizes, int n_in,
                              void* d_out, int out_size, void* d_ws, size_t ws_size,
                              hipStream_t stream) {
  const float* x      = (const float*)d_in[0];
  const int*   ei     = (const int*)d_in[1];
  const float* W_enc  = (const float*)d_in[2];
  const float* b_enc  = (const float*)d_in[3];
  const float* Wg     = (const float*)d_in[4];
  const float* bg     = (const float*)d_in[5];
  const float* gamma  = (const float*)d_in[6];
  const float* beta   = (const float*)d_in[7];
  const float* W_pred = (const float*)d_in[8];
  const float* b_pred = (const float*)d_in[9];
  float* out = (float*)d_out;

  const int* src = ei;
  const int* dst = ei + NE;

  char* p = (char*)d_ws;
  auto alloc = [&](size_t bytes) -> void* {
    void* r = (void*)p;
    p += (bytes + 255) & ~(size_t)255;
    return r;
  };
  float*     hA      = (float*)alloc((size_t)NN * DH * 4);
  float*     hB      = (float*)alloc((size_t)NN * DH * 4);
  _Float16*  msg     = (_Float16*)alloc((size_t)NN * DH * 2);
  _Float16*  agg     = (_Float16*)alloc((size_t)NN * DH * 2);
  int*       rp16    = (int*)alloc((size_t)(NN + 1) * 4);
  int*       pi      = (int*)alloc((size_t)NE * 4);
  int*       cnt     = (int*)alloc((size_t)NN * 4);
  int*       colb    = (int*)alloc((size_t)COLB_CAP * 4);
  int*       bsum    = (int*)alloc((size_t)NBLK * 4);
  float*     stats   = (float*)alloc((size_t)NL * 128 * 4);

  hipMemsetAsync(cnt, 0, (size_t)NN * 4, stream);
  hipMemsetAsync(stats, 0, (size_t)NL * 128 * 4, stream);
  hipMemsetAsync(colb, 0, (size_t)COLB_CAP * 4, stream);  // pads -> row 0 (masked)

  // ---- CSR build (16-padded segments; slot-memo, no atomic in place pass) ----
  k_count2<<<(NE + 255) / 256, 256, 0, stream>>>(dst, cnt, pi);
  k_scan1<<<NBLK, SCAN_B, 0, stream>>>(cnt, rp16, bsum);
  k_scan2<<<1, 128, 0, stream>>>(bsum);
  k_scan3<<<NBLK, SCAN_B, 0, stream>>>(rp16, bsum);
  k_place<<<(NE + 255) / 256, 256, 0, stream>>>(src, dst, rp16, pi, colb);

  // ---- Encoder ----
  k_encoder<<<1024, 256, 0, stream>>>(x, W_enc, b_enc, hA);

  const int MSG_BLOCKS = 1024;
  const int AGG_BLOCKS = NN * 64 / 256;  // one wave per node

  // ---- Layer 0 (no BN; combine uses raw h; msg = relu(h)+eps) ----
  k_msg<<<MSG_BLOCKS, 256, 0, stream>>>(hA, nullptr, nullptr, nullptr, msg);
  k_agg<<<AGG_BLOCKS, 256, 0, stream>>>(msg, rp16, cnt, colb, agg);
  k_mfma<<<LBLK, 256, 0, stream>>>(
      hA, agg, nullptr, nullptr, nullptr, Wg, bg, 0, hB, stats);

  float* h = hB;
  float* hn = hA;
  for (int l = 1; l < NL; ++l) {
    const float* st = stats + (size_t)(l - 1) * 128;
    const float* g  = gamma + (size_t)(l - 1) * DH;
    const float* be = beta + (size_t)(l - 1) * DH;
    k_msg<<<MSG_BLOCKS, 256, 0, stream>>>(h, st, g, be, msg);
    k_agg<<<AGG_BLOCKS, 256, 0, stream>>>(msg, rp16, cnt, colb, agg);
    k_mfma<<<LBLK, 256, 0, stream>>>(
        h, agg, st, g, be,
        Wg + (size_t)l * DH * DH, bg + (size_t)l * DH, 1,
        hn, stats + (size_t)l * 128);
    float* tmp = h; h = hn; hn = tmp;
  }

  // ---- Final BN + ReLU + prediction + log_softmax ----
  k_pred<<<1024, 256, 0, stream>>>(
      h, stats + (size_t)(NL - 1) * 128,
      gamma + (size_t)(NL - 1) * DH, beta + (size_t)(NL - 1) * DH,
      W_pred, b_pred, out);
}

// Round 12
// 761.143 us; speedup vs baseline: 1.2981x; 1.0814x over previous
//
#include <hip/hip_runtime.h>
#include <math.h>

#define NN 100000
#define NE 1000000
#define DH 64
#define DIN 128
#define DOUT 40
#define NL 7
#define SCAN_B 1024
#define NBLK ((NN + SCAN_B - 1) / SCAN_B)  // 98
#define NGRP (NN / 16)     // 6250 16-node groups (exact)
#define LBLK ((NGRP + 3) / 4)
#define COLB_CAP (NE + 16 * NN + 64)  // padded CSR capacity (entries)

typedef _Float16 v8h __attribute__((ext_vector_type(8)));
typedef float v4f __attribute__((ext_vector_type(4)));

// ---------------- CSR build (3-pass, slot-memo, no atomic in place pass) ----------------
__global__ __launch_bounds__(256) void k_count2(const int* __restrict__ dst,
                                                int* __restrict__ cnt,
                                                int* __restrict__ pi) {
  int i = blockIdx.x * 256 + threadIdx.x;
  if (i < NE) pi[i] = atomicAdd(&cnt[dst[i]], 1);
}

// exclusive scan over PADDED counts: ceil16(cnt[i])
__global__ __launch_bounds__(SCAN_B) void k_scan1(const int* __restrict__ cnt,
                                                  int* __restrict__ rp16,
                                                  int* __restrict__ bsum) {
  __shared__ int buf[SCAN_B];
  int i = blockIdx.x * SCAN_B + threadIdx.x;
  int v = (i < NN) ? ((cnt[i] + 15) & ~15) : 0;
  buf[threadIdx.x] = v;
  __syncthreads();
  for (int off = 1; off < SCAN_B; off <<= 1) {
    int t = (threadIdx.x >= off) ? buf[threadIdx.x - off] : 0;
    __syncthreads();
    buf[threadIdx.x] += t;
    __syncthreads();
  }
  if (i < NN) rp16[i] = buf[threadIdx.x] - v;
  if (threadIdx.x == SCAN_B - 1) bsum[blockIdx.x] = buf[SCAN_B - 1];
}

__global__ __launch_bounds__(128) void k_scan2(int* __restrict__ bsum) {
  __shared__ int buf[128];
  int v = (threadIdx.x < NBLK) ? bsum[threadIdx.x] : 0;
  buf[threadIdx.x] = v;
  __syncthreads();
  for (int off = 1; off < 128; off <<= 1) {
    int t = (threadIdx.x >= off) ? buf[threadIdx.x - off] : 0;
    __syncthreads();
    buf[threadIdx.x] += t;
    __syncthreads();
  }
  if (threadIdx.x < NBLK) bsum[threadIdx.x] = buf[threadIdx.x] - v;
}

__global__ __launch_bounds__(SCAN_B) void k_scan3(int* __restrict__ rp16,
                                                  const int* __restrict__ bsum) {
  int i = blockIdx.x * SCAN_B + threadIdx.x;
  if (i < NN) rp16[i] += bsum[blockIdx.x];
}

// place pass: no atomics — slot came from k_count2
// colb stores BYTE offsets into the f16 msg array: src * DH * 2
__global__ __launch_bounds__(256) void k_place(const int* __restrict__ src,
                                               const int* __restrict__ dst,
                                               const int* __restrict__ rp16,
                                               const int* __restrict__ pi,
                                               int* __restrict__ colb) {
  int i = blockIdx.x * 256 + threadIdx.x;
  if (i < NE) colb[rp16[dst[i]] + pi[i]] = src[i] * (DH * 2);
}

// ---------------- Encoder via MFMA: h = x @ W_enc + b_enc ----------------
// One wave = 16 nodes. K = 128 (4 slices of 32), N = 64.
__global__ __launch_bounds__(256) void k_enc_mfma(const float* __restrict__ x,
                                                  const float* __restrict__ W,
                                                  const float* __restrict__ b,
                                                  float* __restrict__ h) {
  __shared__ _Float16 Atile[4][2048];  // per-wave 16 x 128 f16 (256B rows), 4 KB
  const int tid = threadIdx.x;
  const int w = tid >> 6, lane = tid & 63;
  const int gid = blockIdx.x * 4 + w;
  if (gid >= NGRP) return;  // no __syncthreads below
  const int row = lane & 15, hi = lane >> 4;

  // B fragments: lane holds k = kt*32 + hi*8 + j, n = ct*16 + row
  v8h bf[4][4];
#pragma unroll
  for (int kt = 0; kt < 4; ++kt)
#pragma unroll
    for (int ct = 0; ct < 4; ++ct)
#pragma unroll
      for (int j = 0; j < 8; ++j)
        bf[kt][ct][j] = (_Float16)W[(kt * 32 + hi * 8 + j) * DH + ct * 16 + row];

  const int base = gid * 16;
  _Float16* At = &Atile[w][0];
#pragma unroll 4
  for (int i = 0; i < 16; ++i) {
    float v0 = x[(size_t)(base + i) * DIN + lane];
    float v1 = x[(size_t)(base + i) * DIN + 64 + lane];
    int swi = (i & 7) << 4;
    At[(i * 256 + ((lane * 2) ^ swi)) >> 1] = (_Float16)v0;
    At[(i * 256 + 128 + ((lane * 2) ^ swi)) >> 1] = (_Float16)v1;
  }
  const int sw = (row & 7) << 4;
  v8h a[4];
#pragma unroll
  for (int kt = 0; kt < 4; ++kt) {
    int off = (kt & 1) * 64 + hi * 16;
    a[kt] = *(const v8h*)&At[(row * 256 + (kt >> 1) * 128 + (off ^ sw)) >> 1];
  }
  v4f c0 = {0, 0, 0, 0}, c1 = {0, 0, 0, 0}, c2 = {0, 0, 0, 0}, c3 = {0, 0, 0, 0};
#pragma unroll
  for (int kt = 0; kt < 4; ++kt) {
    c0 = __builtin_amdgcn_mfma_f32_16x16x32_f16(a[kt], bf[kt][0], c0, 0, 0, 0);
    c1 = __builtin_amdgcn_mfma_f32_16x16x32_f16(a[kt], bf[kt][1], c1, 0, 0, 0);
    c2 = __builtin_amdgcn_mfma_f32_16x16x32_f16(a[kt], bf[kt][2], c2, 0, 0, 0);
    c3 = __builtin_amdgcn_mfma_f32_16x16x32_f16(a[kt], bf[kt][3], c3, 0, 0, 0);
  }
  float b0 = b[row], b1 = b[16 + row], b2 = b[32 + row], b3 = b[48 + row];
#pragma unroll
  for (int reg = 0; reg < 4; ++reg) {
    size_t o = (size_t)(base + hi * 4 + reg) * DH;
    h[o + row] = c0[reg] + b0;
    h[o + 16 + row] = c1[reg] + b1;
    h[o + 32 + row] = c2[reg] + b2;
    h[o + 48 + row] = c3[reg] + b3;
  }
}

// ---------------- Message precompute: msg = f16(relu(bn(h)) + eps) ----------------
__global__ __launch_bounds__(256) void k_msg(const float* __restrict__ h,
                                             const float* __restrict__ stats_in,
                                             const float* __restrict__ gamma,
                                             const float* __restrict__ beta,
                                             _Float16* __restrict__ msg) {
  int lane = threadIdx.x & 63;
  float scale = 1.f, shift = 0.f;
  if (stats_in) {
    float mu = stats_in[lane] * (1.0f / NN);
    float var = stats_in[64 + lane] * (1.0f / NN) - mu * mu;
    scale = gamma[lane] * rsqrtf(var + 1e-5f);
    shift = beta[lane] - mu * scale;
  }
  int wid = (blockIdx.x * blockDim.x + threadIdx.x) >> 6;
  int nw = (gridDim.x * blockDim.x) >> 6;
  for (int n = wid; n < NN; n += nw) {
    float r = h[n * DH + lane];
    float v = fmaxf(fmaf(r, scale, shift), 0.f) + 1e-7f;
    msg[n * DH + lane] = (_Float16)v;
  }
}

// ---------------- Gather + segment softmax agg: one wave per node ----------------
// R8-proven shape: one fully-coalesced 128B msg row per gather instruction.
__global__ __launch_bounds__(256, 8) void k_agg(const _Float16* __restrict__ msg,
                                                const int* __restrict__ rp16,
                                                const int* __restrict__ cnt,
                                                const int* __restrict__ colb,
                                                _Float16* __restrict__ agg) {
  const int lane = threadIdx.x & 63;
  const int n = (blockIdx.x * 256 + threadIdx.x) >> 6;  // wave-uniform node
  const int beg = rp16[n];  // %16 == 0
  const int deg = cnt[n];
  const char* mb = (const char*)msg + 2 * lane;
  float s = 0.f, t = 0.f;
  for (int j = 0; j < deg; j += 16) {
    int cc[16];
#pragma unroll
    for (int k = 0; k < 16; ++k) cc[k] = colb[beg + j + k];  // padded: safe
    float vv[16];
#pragma unroll
    for (int k = 0; k < 16; ++k) vv[k] = (float)(*(const _Float16*)(mb + cc[k]));
    int rem = deg - j;  // wave-uniform
#pragma unroll
    for (int k = 0; k < 16; ++k) {
      float e = (k < rem) ? __expf(vv[k]) : 0.f;
      s += e;
      t = fmaf(e, vv[k], t);
    }
  }
  agg[(size_t)n * DH + lane] = (_Float16)(t / (s + 1e-16f));
}

// ---------------- MFMA layer: combine(h,agg) -> GEMM (+bias,+res) -> col-stats
//                  One wave = 16 contiguous nodes. ----------------
__global__ __launch_bounds__(256) void k_mfma(
    const float* __restrict__ h_pre, const _Float16* __restrict__ agg,
    const float* __restrict__ stats_in,
    const float* __restrict__ gamma, const float* __restrict__ beta,
    const float* __restrict__ W, const float* __restrict__ b, int add_res,
    float* __restrict__ hout, float* __restrict__ stats_out) {
  __shared__ _Float16 Atile[4][1024];  // per-wave swizzled 16x64 f16 A-tile (8 KB)
  const int tid = threadIdx.x;
  const int w = tid >> 6, lane = tid & 63;
  const int gid = blockIdx.x * 4 + w;
  const int row = lane & 15, hi = lane >> 4;

  float ss0 = 0, ss1 = 0, ss2 = 0, ss3 = 0;
  float qq0 = 0, qq1 = 0, qq2 = 0, qq3 = 0;

  if (gid < NGRP) {  // wave-uniform
    float scale = 1.f, shift = 0.f;
    if (stats_in) {
      float mu = stats_in[lane] * (1.0f / NN);
      float var = stats_in[64 + lane] * (1.0f / NN) - mu * mu;
      scale = gamma[lane] * rsqrtf(var + 1e-5f);
      shift = beta[lane] - mu * scale;
    }
    // B fragments of W (64x64, row-major [k][n]) in f16:
    // lane holds k = kt*32 + hi*8 + j, n = ct*16 + row
    v8h bf[2][4];
#pragma unroll
    for (int kt = 0; kt < 2; ++kt)
#pragma unroll
      for (int ct = 0; ct < 4; ++ct)
#pragma unroll
        for (int j = 0; j < 8; ++j)
          bf[kt][ct][j] = (_Float16)W[(kt * 32 + hi * 8 + j) * DH + ct * 16 + row];

    const int base = gid * 16;
    const float* hl = h_pre + lane;
    const _Float16* agl = agg + lane;
    _Float16* At = &Atile[w][0];

#pragma unroll 4
    for (int i = 0; i < 16; ++i) {
      size_t o = (size_t)(base + i) * DH;
      float raw = hl[o];
      float ag = (float)agl[o];
      float v = stats_in ? fmaxf(fmaf(raw, scale, shift), 0.f) : raw;
      v += ag;
      // swizzled write: row i, feature lane (byte col 2*lane)
      At[(i * 128 + ((lane * 2) ^ ((i & 7) << 4))) >> 1] = (_Float16)v;
    }

    // A fragments: lane reads row=(lane&15), k = kt*32 + hi*8 + j (16B swizzle-stable)
    const int sw = (row & 7) << 4;
    v8h a0 = *(const v8h*)&At[((row * 128) + ((hi * 16) ^ sw)) >> 1];
    v8h a1 = *(const v8h*)&At[((row * 128) + ((64 + hi * 16) ^ sw)) >> 1];
    v4f c0 = {0, 0, 0, 0}, c1 = {0, 0, 0, 0}, c2 = {0, 0, 0, 0}, c3 = {0, 0, 0, 0};
    c0 = __builtin_amdgcn_mfma_f32_16x16x32_f16(a0, bf[0][0], c0, 0, 0, 0);
    c0 = __builtin_amdgcn_mfma_f32_16x16x32_f16(a1, bf[1][0], c0, 0, 0, 0);
    c1 = __builtin_amdgcn_mfma_f32_16x16x32_f16(a0, bf[0][1], c1, 0, 0, 0);
    c1 = __builtin_amdgcn_mfma_f32_16x16x32_f16(a1, bf[1][1], c1, 0, 0, 0);
    c2 = __builtin_amdgcn_mfma_f32_16x16x32_f16(a0, bf[0][2], c2, 0, 0, 0);
    c2 = __builtin_amdgcn_mfma_f32_16x16x32_f16(a1, bf[1][2], c2, 0, 0, 0);
    c3 = __builtin_amdgcn_mfma_f32_16x16x32_f16(a0, bf[0][3], c3, 0, 0, 0);
    c3 = __builtin_amdgcn_mfma_f32_16x16x32_f16(a1, bf[1][3], c3, 0, 0, 0);

    // epilogue in C layout: col = ct*16 + row, node = base + hi*4 + reg
    float b0 = b[row], b1 = b[16 + row], b2 = b[32 + row], b3 = b[48 + row];
#pragma unroll
    for (int reg = 0; reg < 4; ++reg) {
      size_t o = (size_t)(base + hi * 4 + reg) * DH;
      float a0v = c0[reg] + b0;
      float a1v = c1[reg] + b1;
      float a2v = c2[reg] + b2;
      float a3v = c3[reg] + b3;
      if (add_res) {
        a0v += h_pre[o + row];
        a1v += h_pre[o + 16 + row];
        a2v += h_pre[o + 32 + row];
        a3v += h_pre[o + 48 + row];
      }
      hout[o + row] = a0v;
      hout[o + 16 + row] = a1v;
      hout[o + 32 + row] = a2v;
      hout[o + 48 + row] = a3v;
      ss0 += a0v; qq0 = fmaf(a0v, a0v, qq0);
      ss1 += a1v; qq1 = fmaf(a1v, a1v, qq1);
      ss2 += a2v; qq2 = fmaf(a2v, a2v, qq2);
      ss3 += a3v; qq3 = fmaf(a3v, a3v, qq3);
    }
  }

  // reduce across the 4 row-groups (lanes l, l^16, l^32 share column)
#pragma unroll
  for (int off = 16; off <= 32; off <<= 1) {
    ss0 += __shfl_xor(ss0, off, 64); ss1 += __shfl_xor(ss1, off, 64);
    ss2 += __shfl_xor(ss2, off, 64); ss3 += __shfl_xor(ss3, off, 64);
    qq0 += __shfl_xor(qq0, off, 64); qq1 += __shfl_xor(qq1, off, 64);
    qq2 += __shfl_xor(qq2, off, 64); qq3 += __shfl_xor(qq3, off, 64);
  }
  __syncthreads();  // done with f16 A-tiles; reuse LDS as float scratch
  float* Sr = (float*)&Atile[0][0];
  if (lane < 16) {
    Sr[w * 128 + lane] = ss0;       Sr[w * 128 + 16 + lane] = ss1;
    Sr[w * 128 + 32 + lane] = ss2;  Sr[w * 128 + 48 + lane] = ss3;
    Sr[w * 128 + 64 + lane] = qq0;  Sr[w * 128 + 80 + lane] = qq1;
    Sr[w * 128 + 96 + lane] = qq2;  Sr[w * 128 + 112 + lane] = qq3;
  }
  __syncthreads();
  if (tid < 128) {
    float vsum = Sr[tid] + Sr[128 + tid] + Sr[256 + tid] + Sr[384 + tid];
    atomicAdd(&stats_out[tid], vsum);
  }
}

// ---------------- Prediction via MFMA: BN+ReLU -> @W_pred+b -> log_softmax ----
// One wave = 16 nodes. K = 64, N = 48 (cols >= 40 masked to zero weight).
__global__ __launch_bounds__(256) void k_pred_mfma(
    const float* __restrict__ h_pre, const float* __restrict__ stats_in,
    const float* __restrict__ gamma, const float* __restrict__ beta,
    const float* __restrict__ Wp, const float* __restrict__ bp,
    float* __restrict__ out) {
  __shared__ _Float16 Atile[4][1024];
  const int tid = threadIdx.x;
  const int w = tid >> 6, lane = tid & 63;
  const int gid = blockIdx.x * 4 + w;
  if (gid >= NGRP) return;  // no __syncthreads below
  const int row = lane & 15, hi = lane >> 4;

  float mu = stats_in[lane] * (1.0f / NN);
  float var = stats_in[64 + lane] * (1.0f / NN) - mu * mu;
  float scale = gamma[lane] * rsqrtf(var + 1e-5f);
  float shift = beta[lane] - mu * scale;

  // B fragments: lane holds k = kt*32 + hi*8 + j, n = ct*16 + row (n>=40 -> 0)
  v8h bf[2][3];
#pragma unroll
  for (int kt = 0; kt < 2; ++kt)
#pragma unroll
    for (int ct = 0; ct < 3; ++ct) {
      int n = ct * 16 + row;
#pragma unroll
      for (int j = 0; j < 8; ++j)
        bf[kt][ct][j] =
            (n < DOUT) ? (_Float16)Wp[(kt * 32 + hi * 8 + j) * DOUT + n]
                       : (_Float16)0.f;
    }

  const int base = gid * 16;
  const float* hl = h_pre + lane;
  _Float16* At = &Atile[w][0];
#pragma unroll 4
  for (int i = 0; i < 16; ++i) {
    float raw = hl[(size_t)(base + i) * DH];
    float v = fmaxf(fmaf(raw, scale, shift), 0.f);
    At[(i * 128 + ((lane * 2) ^ ((i & 7) << 4))) >> 1] = (_Float16)v;
  }
  const int sw = (row & 7) << 4;
  v8h a0 = *(const v8h*)&At[((row * 128) + ((hi * 16) ^ sw)) >> 1];
  v8h a1 = *(const v8h*)&At[((row * 128) + ((64 + hi * 16) ^ sw)) >> 1];
  v4f c0 = {0, 0, 0, 0}, c1 = {0, 0, 0, 0}, c2 = {0, 0, 0, 0};
  c0 = __builtin_amdgcn_mfma_f32_16x16x32_f16(a0, bf[0][0], c0, 0, 0, 0);
  c0 = __builtin_amdgcn_mfma_f32_16x16x32_f16(a1, bf[1][0], c0, 0, 0, 0);
  c1 = __builtin_amdgcn_mfma_f32_16x16x32_f16(a0, bf[0][1], c1, 0, 0, 0);
  c1 = __builtin_amdgcn_mfma_f32_16x16x32_f16(a1, bf[1][1], c1, 0, 0, 0);
  c2 = __builtin_amdgcn_mfma_f32_16x16x32_f16(a0, bf[0][2], c2, 0, 0, 0);
  c2 = __builtin_amdgcn_mfma_f32_16x16x32_f16(a1, bf[1][2], c2, 0, 0, 0);

  // log_softmax per node: node = base + hi*4 + reg, cols = {row, 16+row, 32+row}
  float bp0 = bp[row], bp1 = bp[16 + row];
  float bp2 = (32 + row < DOUT) ? bp[32 + row] : 0.f;
  bool v2 = (32 + row) < DOUT;
#pragma unroll
  for (int reg = 0; reg < 4; ++reg) {
    float l0 = c0[reg] + bp0;
    float l1 = c1[reg] + bp1;
    float l2 = v2 ? (c2[reg] + bp2) : -INFINITY;
    float xm = fmaxf(fmaxf(l0, l1), l2);
#pragma unroll
    for (int off = 1; off <= 8; off <<= 1) xm = fmaxf(xm, __shfl_xor(xm, off, 64));
    float e = __expf(l0 - xm) + __expf(l1 - xm) + (v2 ? __expf(l2 - xm) : 0.f);
#pragma unroll
    for (int off = 1; off <= 8; off <<= 1) e += __shfl_xor(e, off, 64);
    float ls = xm + __logf(e);
    size_t o = (size_t)(base + hi * 4 + reg) * DOUT;
    out[o + row] = l0 - ls;
    out[o + 16 + row] = l1 - ls;
    if (v2) out[o + 32 + row] = l2 - ls;
  }
}

extern "C" void kernel_launch(void* const* d_in, const int* in_sizes, int n_in,
                              void* d_out, int out_size, void* d_ws, size_t ws_size,
                              hipStream_t stream) {
  const float* x      = (const float*)d_in[0];
  const int*   ei     = (const int*)d_in[1];
  const float* W_enc  = (const float*)d_in[2];
  const float* b_enc  = (const float*)d_in[3];
  const float* Wg     = (const float*)d_in[4];
  const float* bg     = (const float*)d_in[5];
  const float* gamma  = (const float*)d_in[6];
  const float* beta   = (const float*)d_in[7];
  const float* W_pred = (const float*)d_in[8];
  const float* b_pred = (const float*)d_in[9];
  float* out = (float*)d_out;

  const int* src = ei;
  const int* dst = ei + NE;

  char* p = (char*)d_ws;
  auto alloc = [&](size_t bytes) -> void* {
    void* r = (void*)p;
    p += (bytes + 255) & ~(size_t)255;
    return r;
  };
  float*     hA      = (float*)alloc((size_t)NN * DH * 4);
  float*     hB      = (float*)alloc((size_t)NN * DH * 4);
  _Float16*  msg     = (_Float16*)alloc((size_t)NN * DH * 2);
  _Float16*  agg     = (_Float16*)alloc((size_t)NN * DH * 2);
  int*       rp16    = (int*)alloc((size_t)(NN + 1) * 4);
  int*       pi      = (int*)alloc((size_t)NE * 4);
  int*       cnt     = (int*)alloc((size_t)NN * 4);
  int*       colb    = (int*)alloc((size_t)COLB_CAP * 4);
  int*       bsum    = (int*)alloc((size_t)NBLK * 4);
  float*     stats   = (float*)alloc((size_t)NL * 128 * 4);

  hipMemsetAsync(cnt, 0, (size_t)NN * 4, stream);
  hipMemsetAsync(stats, 0, (size_t)NL * 128 * 4, stream);
  hipMemsetAsync(colb, 0, (size_t)COLB_CAP * 4, stream);  // pads -> row 0 (masked)

  // ---- CSR build (16-padded segments; slot-memo, no atomic in place pass) ----
  k_count2<<<(NE + 255) / 256, 256, 0, stream>>>(dst, cnt, pi);
  k_scan1<<<NBLK, SCAN_B, 0, stream>>>(cnt, rp16, bsum);
  k_scan2<<<1, 128, 0, stream>>>(bsum);
  k_scan3<<<NBLK, SCAN_B, 0, stream>>>(rp16, bsum);
  k_place<<<(NE + 255) / 256, 256, 0, stream>>>(src, dst, rp16, pi, colb);

  // ---- Encoder (MFMA) ----
  k_enc_mfma<<<LBLK, 256, 0, stream>>>(x, W_enc, b_enc, hA);

  const int MSG_BLOCKS = 1024;
  const int AGG_BLOCKS = NN * 64 / 256;  // one wave per node

  // ---- Layer 0 (no BN; combine uses raw h; msg = relu(h)+eps) ----
  k_msg<<<MSG_BLOCKS, 256, 0, stream>>>(hA, nullptr, nullptr, nullptr, msg);
  k_agg<<<AGG_BLOCKS, 256, 0, stream>>>(msg, rp16, cnt, colb, agg);
  k_mfma<<<LBLK, 256, 0, stream>>>(
      hA, agg, nullptr, nullptr, nullptr, Wg, bg, 0, hB, stats);

  float* h = hB;
  float* hn = hA;
  for (int l = 1; l < NL; ++l) {
    const float* st = stats + (size_t)(l - 1) * 128;
    const float* g  = gamma + (size_t)(l - 1) * DH;
    const float* be = beta + (size_t)(l - 1) * DH;
    k_msg<<<MSG_BLOCKS, 256, 0, stream>>>(h, st, g, be, msg);
    k_agg<<<AGG_BLOCKS, 256, 0, stream>>>(msg, rp16, cnt, colb, agg);
    k_mfma<<<LBLK, 256, 0, stream>>>(
        h, agg, st, g, be,
        Wg + (size_t)l * DH * DH, bg + (size_t)l * DH, 1,
        hn, stats + (size_t)l * 128);
    float* tmp = h; h = hn; hn = tmp;
  }

  // ---- Final BN + ReLU + prediction + log_softmax (MFMA) ----
  k_pred_mfma<<<LBLK, 256, 0, stream>>>(
      h, stats + (size_t)(NL - 1) * 128,
      gamma + (size_t)(NL - 1) * DH, beta + (size_t)(NL - 1) * DH,
      W_pred, b_pred, out);
}

// Round 13
// 576.346 us; speedup vs baseline: 1.7144x; 1.3206x over previous
//
#include <hip/hip_runtime.h>
#include <math.h>

#define NN 100000
#define NE 1000000
#define DH 64
#define DIN 128
#define DOUT 40
#define NL 7
#define SCAN_B 1024
#define NBLK ((NN + SCAN_B - 1) / SCAN_B)  // 98
#define NGRP (NN / 16)     // 6250 16-node groups (exact)
#define LBLK ((NGRP + 3) / 4)              // 1563 blocks for MFMA kernels
#define COLB_CAP (NE + 16 * NN + 64)  // padded CSR capacity (entries)

typedef _Float16 v8h __attribute__((ext_vector_type(8)));
typedef float v4f __attribute__((ext_vector_type(4)));

// ---------------- CSR build (3-pass, slot-memo, no atomic in place pass) ----------------
__global__ __launch_bounds__(256) void k_count2(const int* __restrict__ dst,
                                                int* __restrict__ cnt,
                                                int* __restrict__ pi) {
  int i = blockIdx.x * 256 + threadIdx.x;
  if (i < NE) pi[i] = atomicAdd(&cnt[dst[i]], 1);
}

// exclusive scan over PADDED counts: ceil16(cnt[i])
__global__ __launch_bounds__(SCAN_B) void k_scan1(const int* __restrict__ cnt,
                                                  int* __restrict__ rp16,
                                                  int* __restrict__ bsum) {
  __shared__ int buf[SCAN_B];
  int i = blockIdx.x * SCAN_B + threadIdx.x;
  int v = (i < NN) ? ((cnt[i] + 15) & ~15) : 0;
  buf[threadIdx.x] = v;
  __syncthreads();
  for (int off = 1; off < SCAN_B; off <<= 1) {
    int t = (threadIdx.x >= off) ? buf[threadIdx.x - off] : 0;
    __syncthreads();
    buf[threadIdx.x] += t;
    __syncthreads();
  }
  if (i < NN) rp16[i] = buf[threadIdx.x] - v;
  if (threadIdx.x == SCAN_B - 1) bsum[blockIdx.x] = buf[SCAN_B - 1];
}

__global__ __launch_bounds__(128) void k_scan2(int* __restrict__ bsum) {
  __shared__ int buf[128];
  int v = (threadIdx.x < NBLK) ? bsum[threadIdx.x] : 0;
  buf[threadIdx.x] = v;
  __syncthreads();
  for (int off = 1; off < 128; off <<= 1) {
    int t = (threadIdx.x >= off) ? buf[threadIdx.x - off] : 0;
    __syncthreads();
    buf[threadIdx.x] += t;
    __syncthreads();
  }
  if (threadIdx.x < NBLK) bsum[threadIdx.x] = buf[threadIdx.x] - v;
}

__global__ __launch_bounds__(SCAN_B) void k_scan3(int* __restrict__ rp16,
                                                  const int* __restrict__ bsum) {
  int i = blockIdx.x * SCAN_B + threadIdx.x;
  if (i < NN) rp16[i] += bsum[blockIdx.x];
}

// place pass: no atomics — slot came from k_count2
// colb stores BYTE offsets into the f16 msg array: src * DH * 2
__global__ __launch_bounds__(256) void k_place(const int* __restrict__ src,
                                               const int* __restrict__ dst,
                                               const int* __restrict__ rp16,
                                               const int* __restrict__ pi,
                                               int* __restrict__ colb) {
  int i = blockIdx.x * 256 + threadIdx.x;
  if (i < NE) colb[rp16[dst[i]] + pi[i]] = src[i] * (DH * 2);
}

// ---------------- Encoder via MFMA: h = x @ W_enc + b_enc ----------------
__global__ __launch_bounds__(256) void k_enc_mfma(const float* __restrict__ x,
                                                  const float* __restrict__ W,
                                                  const float* __restrict__ b,
                                                  float* __restrict__ h) {
  __shared__ _Float16 Atile[4][2048];  // per-wave 16 x 128 f16 (256B rows)
  const int tid = threadIdx.x;
  const int w = tid >> 6, lane = tid & 63;
  const int gid = blockIdx.x * 4 + w;
  if (gid >= NGRP) return;  // no __syncthreads below
  const int row = lane & 15, hi = lane >> 4;

  v8h bf[4][4];
#pragma unroll
  for (int kt = 0; kt < 4; ++kt)
#pragma unroll
    for (int ct = 0; ct < 4; ++ct)
#pragma unroll
      for (int j = 0; j < 8; ++j)
        bf[kt][ct][j] = (_Float16)W[(kt * 32 + hi * 8 + j) * DH + ct * 16 + row];

  const int base = gid * 16;
  _Float16* At = &Atile[w][0];
#pragma unroll 4
  for (int i = 0; i < 16; ++i) {
    float v0 = x[(size_t)(base + i) * DIN + lane];
    float v1 = x[(size_t)(base + i) * DIN + 64 + lane];
    int swi = (i & 7) << 4;
    At[(i * 256 + ((lane * 2) ^ swi)) >> 1] = (_Float16)v0;
    At[(i * 256 + 128 + ((lane * 2) ^ swi)) >> 1] = (_Float16)v1;
  }
  const int sw = (row & 7) << 4;
  v8h a[4];
#pragma unroll
  for (int kt = 0; kt < 4; ++kt) {
    int off = (kt & 1) * 64 + hi * 16;
    a[kt] = *(const v8h*)&At[(row * 256 + (kt >> 1) * 128 + (off ^ sw)) >> 1];
  }
  v4f c0 = {0, 0, 0, 0}, c1 = {0, 0, 0, 0}, c2 = {0, 0, 0, 0}, c3 = {0, 0, 0, 0};
#pragma unroll
  for (int kt = 0; kt < 4; ++kt) {
    c0 = __builtin_amdgcn_mfma_f32_16x16x32_f16(a[kt], bf[kt][0], c0, 0, 0, 0);
    c1 = __builtin_amdgcn_mfma_f32_16x16x32_f16(a[kt], bf[kt][1], c1, 0, 0, 0);
    c2 = __builtin_amdgcn_mfma_f32_16x16x32_f16(a[kt], bf[kt][2], c2, 0, 0, 0);
    c3 = __builtin_amdgcn_mfma_f32_16x16x32_f16(a[kt], bf[kt][3], c3, 0, 0, 0);
  }
  float b0 = b[row], b1 = b[16 + row], b2 = b[32 + row], b3 = b[48 + row];
#pragma unroll
  for (int reg = 0; reg < 4; ++reg) {
    size_t o = (size_t)(base + hi * 4 + reg) * DH;
    h[o + row] = c0[reg] + b0;
    h[o + 16 + row] = c1[reg] + b1;
    h[o + 32 + row] = c2[reg] + b2;
    h[o + 48 + row] = c3[reg] + b3;
  }
}

// ---------------- Message precompute: msg = f16(relu(bn(h)) + eps) ----------------
__global__ __launch_bounds__(256) void k_msg(const float* __restrict__ h,
                                             const float* __restrict__ stats_in,
                                             const float* __restrict__ gamma,
                                             const float* __restrict__ beta,
                                             _Float16* __restrict__ msg) {
  int lane = threadIdx.x & 63;
  float scale = 1.f, shift = 0.f;
  if (stats_in) {
    float mu = stats_in[lane] * (1.0f / NN);
    float var = stats_in[64 + lane] * (1.0f / NN) - mu * mu;
    scale = gamma[lane] * rsqrtf(var + 1e-5f);
    shift = beta[lane] - mu * scale;
  }
  int wid = (blockIdx.x * blockDim.x + threadIdx.x) >> 6;
  int nw = (gridDim.x * blockDim.x) >> 6;
  for (int n = wid; n < NN; n += nw) {
    float r = h[n * DH + lane];
    float v = fmaxf(fmaf(r, scale, shift), 0.f) + 1e-7f;
    msg[n * DH + lane] = (_Float16)v;
  }
}

// ---------------- Gather + segment softmax agg: one wave per node ----------------
__global__ __launch_bounds__(256, 8) void k_agg(const _Float16* __restrict__ msg,
                                                const int* __restrict__ rp16,
                                                const int* __restrict__ cnt,
                                                const int* __restrict__ colb,
                                                _Float16* __restrict__ agg) {
  const int lane = threadIdx.x & 63;
  const int n = (blockIdx.x * 256 + threadIdx.x) >> 6;  // wave-uniform node
  const int beg = rp16[n];  // %16 == 0
  const int deg = cnt[n];
  const char* mb = (const char*)msg + 2 * lane;
  float s = 0.f, t = 0.f;
  for (int j = 0; j < deg; j += 16) {
    int cc[16];
#pragma unroll
    for (int k = 0; k < 16; ++k) cc[k] = colb[beg + j + k];  // padded: safe
    float vv[16];
#pragma unroll
    for (int k = 0; k < 16; ++k) vv[k] = (float)(*(const _Float16*)(mb + cc[k]));
    int rem = deg - j;  // wave-uniform
#pragma unroll
    for (int k = 0; k < 16; ++k) {
      float e = (k < rem) ? __expf(vv[k]) : 0.f;
      s += e;
      t = fmaf(e, vv[k], t);
    }
  }
  agg[(size_t)n * DH + lane] = (_Float16)(t / (s + 1e-16f));
}

// ---------------- MFMA layer: combine(h,agg) -> GEMM (+bias,+res) ->
//                  per-block col-stat partials (NO atomics) ----------------
__global__ __launch_bounds__(256) void k_mfma(
    const float* __restrict__ h_pre, const _Float16* __restrict__ agg,
    const float* __restrict__ stats_in,
    const float* __restrict__ gamma, const float* __restrict__ beta,
    const float* __restrict__ W, const float* __restrict__ b, int add_res,
    float* __restrict__ hout, float* __restrict__ partial) {
  __shared__ _Float16 Atile[4][1024];  // per-wave swizzled 16x64 f16 A-tile
  const int tid = threadIdx.x;
  const int w = tid >> 6, lane = tid & 63;
  const int gid = blockIdx.x * 4 + w;
  const int row = lane & 15, hi = lane >> 4;

  float ss0 = 0, ss1 = 0, ss2 = 0, ss3 = 0;
  float qq0 = 0, qq1 = 0, qq2 = 0, qq3 = 0;

  if (gid < NGRP) {  // wave-uniform
    float scale = 1.f, shift = 0.f;
    if (stats_in) {
      float mu = stats_in[lane] * (1.0f / NN);
      float var = stats_in[64 + lane] * (1.0f / NN) - mu * mu;
      scale = gamma[lane] * rsqrtf(var + 1e-5f);
      shift = beta[lane] - mu * scale;
    }
    v8h bf[2][4];
#pragma unroll
    for (int kt = 0; kt < 2; ++kt)
#pragma unroll
      for (int ct = 0; ct < 4; ++ct)
#pragma unroll
        for (int j = 0; j < 8; ++j)
          bf[kt][ct][j] = (_Float16)W[(kt * 32 + hi * 8 + j) * DH + ct * 16 + row];

    const int base = gid * 16;
    const float* hl = h_pre + lane;
    const _Float16* agl = agg + lane;
    _Float16* At = &Atile[w][0];

    // ---- load phase: ALL independent loads issued up front ----
    float rawv[16], agv[16];
#pragma unroll
    for (int i = 0; i < 16; ++i) {
      size_t o = (size_t)(base + i) * DH;
      rawv[i] = hl[o];
      agv[i] = (float)agl[o];
    }
    float res[4][4];
    if (add_res) {
#pragma unroll
      for (int reg = 0; reg < 4; ++reg) {
        size_t o = (size_t)(base + hi * 4 + reg) * DH;
        res[reg][0] = h_pre[o + row];
        res[reg][1] = h_pre[o + 16 + row];
        res[reg][2] = h_pre[o + 32 + row];
        res[reg][3] = h_pre[o + 48 + row];
      }
    }
    // ---- convert + swizzled LDS write ----
#pragma unroll
    for (int i = 0; i < 16; ++i) {
      float v = stats_in ? fmaxf(fmaf(rawv[i], scale, shift), 0.f) : rawv[i];
      v += agv[i];
      At[(i * 128 + ((lane * 2) ^ ((i & 7) << 4))) >> 1] = (_Float16)v;
    }
    const int sw = (row & 7) << 4;
    v8h a0 = *(const v8h*)&At[((row * 128) + ((hi * 16) ^ sw)) >> 1];
    v8h a1 = *(const v8h*)&At[((row * 128) + ((64 + hi * 16) ^ sw)) >> 1];
    v4f c0 = {0, 0, 0, 0}, c1 = {0, 0, 0, 0}, c2 = {0, 0, 0, 0}, c3 = {0, 0, 0, 0};
    c0 = __builtin_amdgcn_mfma_f32_16x16x32_f16(a0, bf[0][0], c0, 0, 0, 0);
    c0 = __builtin_amdgcn_mfma_f32_16x16x32_f16(a1, bf[1][0], c0, 0, 0, 0);
    c1 = __builtin_amdgcn_mfma_f32_16x16x32_f16(a0, bf[0][1], c1, 0, 0, 0);
    c1 = __builtin_amdgcn_mfma_f32_16x16x32_f16(a1, bf[1][1], c1, 0, 0, 0);
    c2 = __builtin_amdgcn_mfma_f32_16x16x32_f16(a0, bf[0][2], c2, 0, 0, 0);
    c2 = __builtin_amdgcn_mfma_f32_16x16x32_f16(a1, bf[1][2], c2, 0, 0, 0);
    c3 = __builtin_amdgcn_mfma_f32_16x16x32_f16(a0, bf[0][3], c3, 0, 0, 0);
    c3 = __builtin_amdgcn_mfma_f32_16x16x32_f16(a1, bf[1][3], c3, 0, 0, 0);

    float b0 = b[row], b1 = b[16 + row], b2 = b[32 + row], b3 = b[48 + row];
#pragma unroll
    for (int reg = 0; reg < 4; ++reg) {
      size_t o = (size_t)(base + hi * 4 + reg) * DH;
      float a0v = c0[reg] + b0;
      float a1v = c1[reg] + b1;
      float a2v = c2[reg] + b2;
      float a3v = c3[reg] + b3;
      if (add_res) {
        a0v += res[reg][0];
        a1v += res[reg][1];
        a2v += res[reg][2];
        a3v += res[reg][3];
      }
      hout[o + row] = a0v;
      hout[o + 16 + row] = a1v;
      hout[o + 32 + row] = a2v;
      hout[o + 48 + row] = a3v;
      ss0 += a0v; qq0 = fmaf(a0v, a0v, qq0);
      ss1 += a1v; qq1 = fmaf(a1v, a1v, qq1);
      ss2 += a2v; qq2 = fmaf(a2v, a2v, qq2);
      ss3 += a3v; qq3 = fmaf(a3v, a3v, qq3);
    }
  }

  // reduce across the 4 row-groups (lanes l, l^16, l^32 share column)
#pragma unroll
  for (int off = 16; off <= 32; off <<= 1) {
    ss0 += __shfl_xor(ss0, off, 64); ss1 += __shfl_xor(ss1, off, 64);
    ss2 += __shfl_xor(ss2, off, 64); ss3 += __shfl_xor(ss3, off, 64);
    qq0 += __shfl_xor(qq0, off, 64); qq1 += __shfl_xor(qq1, off, 64);
    qq2 += __shfl_xor(qq2, off, 64); qq3 += __shfl_xor(qq3, off, 64);
  }
  __syncthreads();  // done with f16 A-tiles; reuse LDS as float scratch
  float* Sr = (float*)&Atile[0][0];
  if (lane < 16) {
    Sr[w * 128 + lane] = ss0;       Sr[w * 128 + 16 + lane] = ss1;
    Sr[w * 128 + 32 + lane] = ss2;  Sr[w * 128 + 48 + lane] = ss3;
    Sr[w * 128 + 64 + lane] = qq0;  Sr[w * 128 + 80 + lane] = qq1;
    Sr[w * 128 + 96 + lane] = qq2;  Sr[w * 128 + 112 + lane] = qq3;
  }
  __syncthreads();
  if (tid < 128) {
    float vsum = Sr[tid] + Sr[128 + tid] + Sr[256 + tid] + Sr[384 + tid];
    partial[(size_t)blockIdx.x * 128 + tid] = vsum;  // plain store, no atomic
  }
}

// ---------------- Partial-stats reduction: stats[f] = sum over blocks ----------------
__global__ __launch_bounds__(256) void k_red(const float* __restrict__ partial,
                                             float* __restrict__ stats) {
  const int f = blockIdx.x;  // 0..127
  float acc = 0.f;
  for (int i = threadIdx.x; i < LBLK; i += 256)
    acc += partial[(size_t)i * 128 + f];
  __shared__ float buf[256];
  buf[threadIdx.x] = acc;
  __syncthreads();
  for (int off = 128; off >= 1; off >>= 1) {
    if (threadIdx.x < off) buf[threadIdx.x] += buf[threadIdx.x + off];
    __syncthreads();
  }
  if (threadIdx.x == 0) stats[f] = buf[0];
}

// ---------------- Prediction via MFMA: BN+ReLU -> @W_pred+b -> log_softmax ----
__global__ __launch_bounds__(256) void k_pred_mfma(
    const float* __restrict__ h_pre, const float* __restrict__ stats_in,
    const float* __restrict__ gamma, const float* __restrict__ beta,
    const float* __restrict__ Wp, const float* __restrict__ bp,
    float* __restrict__ out) {
  __shared__ _Float16 Atile[4][1024];
  const int tid = threadIdx.x;
  const int w = tid >> 6, lane = tid & 63;
  const int gid = blockIdx.x * 4 + w;
  if (gid >= NGRP) return;  // no __syncthreads below
  const int row = lane & 15, hi = lane >> 4;

  float mu = stats_in[lane] * (1.0f / NN);
  float var = stats_in[64 + lane] * (1.0f / NN) - mu * mu;
  float scale = gamma[lane] * rsqrtf(var + 1e-5f);
  float shift = beta[lane] - mu * scale;

  v8h bf[2][3];
#pragma unroll
  for (int kt = 0; kt < 2; ++kt)
#pragma unroll
    for (int ct = 0; ct < 3; ++ct) {
      int n = ct * 16 + row;
#pragma unroll
      for (int j = 0; j < 8; ++j)
        bf[kt][ct][j] =
            (n < DOUT) ? (_Float16)Wp[(kt * 32 + hi * 8 + j) * DOUT + n]
                       : (_Float16)0.f;
    }

  const int base = gid * 16;
  const float* hl = h_pre + lane;
  _Float16* At = &Atile[w][0];
#pragma unroll 4
  for (int i = 0; i < 16; ++i) {
    float raw = hl[(size_t)(base + i) * DH];
    float v = fmaxf(fmaf(raw, scale, shift), 0.f);
    At[(i * 128 + ((lane * 2) ^ ((i & 7) << 4))) >> 1] = (_Float16)v;
  }
  const int sw = (row & 7) << 4;
  v8h a0 = *(const v8h*)&At[((row * 128) + ((hi * 16) ^ sw)) >> 1];
  v8h a1 = *(const v8h*)&At[((row * 128) + ((64 + hi * 16) ^ sw)) >> 1];
  v4f c0 = {0, 0, 0, 0}, c1 = {0, 0, 0, 0}, c2 = {0, 0, 0, 0};
  c0 = __builtin_amdgcn_mfma_f32_16x16x32_f16(a0, bf[0][0], c0, 0, 0, 0);
  c0 = __builtin_amdgcn_mfma_f32_16x16x32_f16(a1, bf[1][0], c0, 0, 0, 0);
  c1 = __builtin_amdgcn_mfma_f32_16x16x32_f16(a0, bf[0][1], c1, 0, 0, 0);
  c1 = __builtin_amdgcn_mfma_f32_16x16x32_f16(a1, bf[1][1], c1, 0, 0, 0);
  c2 = __builtin_amdgcn_mfma_f32_16x16x32_f16(a0, bf[0][2], c2, 0, 0, 0);
  c2 = __builtin_amdgcn_mfma_f32_16x16x32_f16(a1, bf[1][2], c2, 0, 0, 0);

  float bp0 = bp[row], bp1 = bp[16 + row];
  float bp2 = (32 + row < DOUT) ? bp[32 + row] : 0.f;
  bool v2 = (32 + row) < DOUT;
#pragma unroll
  for (int reg = 0; reg < 4; ++reg) {
    float l0 = c0[reg] + bp0;
    float l1 = c1[reg] + bp1;
    float l2 = v2 ? (c2[reg] + bp2) : -INFINITY;
    float xm = fmaxf(fmaxf(l0, l1), l2);
#pragma unroll
    for (int off = 1; off <= 8; off <<= 1) xm = fmaxf(xm, __shfl_xor(xm, off, 64));
    float e = __expf(l0 - xm) + __expf(l1 - xm) + (v2 ? __expf(l2 - xm) : 0.f);
#pragma unroll
    for (int off = 1; off <= 8; off <<= 1) e += __shfl_xor(e, off, 64);
    float ls = xm + __logf(e);
    size_t o = (size_t)(base + hi * 4 + reg) * DOUT;
    out[o + row] = l0 - ls;
    out[o + 16 + row] = l1 - ls;
    if (v2) out[o + 32 + row] = l2 - ls;
  }
}

extern "C" void kernel_launch(void* const* d_in, const int* in_sizes, int n_in,
                              void* d_out, int out_size, void* d_ws, size_t ws_size,
                              hipStream_t stream) {
  const float* x      = (const float*)d_in[0];
  const int*   ei     = (const int*)d_in[1];
  const float* W_enc  = (const float*)d_in[2];
  const float* b_enc  = (const float*)d_in[3];
  const float* Wg     = (const float*)d_in[4];
  const float* bg     = (const float*)d_in[5];
  const float* gamma  = (const float*)d_in[6];
  const float* beta   = (const float*)d_in[7];
  const float* W_pred = (const float*)d_in[8];
  const float* b_pred = (const float*)d_in[9];
  float* out = (float*)d_out;

  const int* src = ei;
  const int* dst = ei + NE;

  char* p = (char*)d_ws;
  auto alloc = [&](size_t bytes) -> void* {
    void* r = (void*)p;
    p += (bytes + 255) & ~(size_t)255;
    return r;
  };
  float*     hA      = (float*)alloc((size_t)NN * DH * 4);
  float*     hB      = (float*)alloc((size_t)NN * DH * 4);
  _Float16*  msg     = (_Float16*)alloc((size_t)NN * DH * 2);
  _Float16*  agg     = (_Float16*)alloc((size_t)NN * DH * 2);
  int*       rp16    = (int*)alloc((size_t)(NN + 1) * 4);
  int*       pi      = (int*)alloc((size_t)NE * 4);
  int*       cnt     = (int*)alloc((size_t)NN * 4);
  int*       colb    = (int*)alloc((size_t)COLB_CAP * 4);
  int*       bsum    = (int*)alloc((size_t)NBLK * 4);
  float*     stats   = (float*)alloc((size_t)NL * 128 * 4);
  float*     partial = (float*)alloc((size_t)LBLK * 128 * 4);

  hipMemsetAsync(cnt, 0, (size_t)NN * 4, stream);
  hipMemsetAsync(colb, 0, (size_t)COLB_CAP * 4, stream);  // pads -> row 0 (masked)

  // ---- CSR build (16-padded segments; slot-memo, no atomic in place pass) ----
  k_count2<<<(NE + 255) / 256, 256, 0, stream>>>(dst, cnt, pi);
  k_scan1<<<NBLK, SCAN_B, 0, stream>>>(cnt, rp16, bsum);
  k_scan2<<<1, 128, 0, stream>>>(bsum);
  k_scan3<<<NBLK, SCAN_B, 0, stream>>>(rp16, bsum);
  k_place<<<(NE + 255) / 256, 256, 0, stream>>>(src, dst, rp16, pi, colb);

  // ---- Encoder (MFMA) ----
  k_enc_mfma<<<LBLK, 256, 0, stream>>>(x, W_enc, b_enc, hA);

  const int MSG_BLOCKS = 1024;
  const int AGG_BLOCKS = NN * 64 / 256;  // one wave per node

  // ---- Layer 0 (no BN; combine uses raw h; msg = relu(h)+eps) ----
  k_msg<<<MSG_BLOCKS, 256, 0, stream>>>(hA, nullptr, nullptr, nullptr, msg);
  k_agg<<<AGG_BLOCKS, 256, 0, stream>>>(msg, rp16, cnt, colb, agg);
  k_mfma<<<LBLK, 256, 0, stream>>>(
      hA, agg, nullptr, nullptr, nullptr, Wg, bg, 0, hB, partial);
  k_red<<<128, 256, 0, stream>>>(partial, stats);

  float* h = hB;
  float* hn = hA;
  for (int l = 1; l < NL; ++l) {
    const float* st = stats + (size_t)(l - 1) * 128;
    const float* g  = gamma + (size_t)(l - 1) * DH;
    const float* be = beta + (size_t)(l - 1) * DH;
    k_msg<<<MSG_BLOCKS, 256, 0, stream>>>(h, st, g, be, msg);
    k_agg<<<AGG_BLOCKS, 256, 0, stream>>>(msg, rp16, cnt, colb, agg);
    k_mfma<<<LBLK, 256, 0, stream>>>(
        h, agg, st, g, be,
        Wg + (size_t)l * DH * DH, bg + (size_t)l * DH, 1,
        hn, partial);
    k_red<<<128, 256, 0, stream>>>(partial, stats + (size_t)l * 128);
    float* tmp = h; h = hn; hn = tmp;
  }

  // ---- Final BN + ReLU + prediction + log_softmax (MFMA) ----
  k_pred_mfma<<<LBLK, 256, 0, stream>>>(
      h, stats + (size_t)(NL - 1) * 128,
      gamma + (size_t)(NL - 1) * DH, beta + (size_t)(NL - 1) * DH,
      W_pred, b_pred, out);
}

// Round 14
// 554.043 us; speedup vs baseline: 1.7834x; 1.0403x over previous
//
#include <hip/hip_runtime.h>
#include <math.h>

#define NN 100000
#define NE 1000000
#define DH 64
#define DIN 128
#define DOUT 40
#define NL 7
#define SCAN_B 1024
#define NBLK ((NN + SCAN_B - 1) / SCAN_B)  // 98
#define NGRP (NN / 16)     // 6250 16-node groups (exact)
#define LBLK ((NGRP + 3) / 4)              // 1563 blocks for MFMA kernels
#define COLB_CAP (NE + 16 * NN + 64)  // padded CSR capacity (entries)
#define QS 16.0f           // int8 quant scale: q = round(v*QS), v' = q/QS
#define IQS 0.0625f

typedef _Float16 v8h __attribute__((ext_vector_type(8)));
typedef float v4f __attribute__((ext_vector_type(4)));

// ---------------- CSR build (3-pass, slot-memo, no atomic in place pass) ----------------
__global__ __launch_bounds__(256) void k_count2(const int* __restrict__ dst,
                                                int* __restrict__ cnt,
                                                int* __restrict__ pi) {
  int i = blockIdx.x * 256 + threadIdx.x;
  if (i < NE) pi[i] = atomicAdd(&cnt[dst[i]], 1);
}

// exclusive scan over PADDED counts: ceil16(cnt[i])
__global__ __launch_bounds__(SCAN_B) void k_scan1(const int* __restrict__ cnt,
                                                  int* __restrict__ rp16,
                                                  int* __restrict__ bsum) {
  __shared__ int buf[SCAN_B];
  int i = blockIdx.x * SCAN_B + threadIdx.x;
  int v = (i < NN) ? ((cnt[i] + 15) & ~15) : 0;
  buf[threadIdx.x] = v;
  __syncthreads();
  for (int off = 1; off < SCAN_B; off <<= 1) {
    int t = (threadIdx.x >= off) ? buf[threadIdx.x - off] : 0;
    __syncthreads();
    buf[threadIdx.x] += t;
    __syncthreads();
  }
  if (i < NN) rp16[i] = buf[threadIdx.x] - v;
  if (threadIdx.x == SCAN_B - 1) bsum[blockIdx.x] = buf[SCAN_B - 1];
}

__global__ __launch_bounds__(128) void k_scan2(int* __restrict__ bsum) {
  __shared__ int buf[128];
  int v = (threadIdx.x < NBLK) ? bsum[threadIdx.x] : 0;
  buf[threadIdx.x] = v;
  __syncthreads();
  for (int off = 1; off < 128; off <<= 1) {
    int t = (threadIdx.x >= off) ? buf[threadIdx.x - off] : 0;
    __syncthreads();
    buf[threadIdx.x] += t;
    __syncthreads();
  }
  if (threadIdx.x < NBLK) bsum[threadIdx.x] = buf[threadIdx.x] - v;
}

__global__ __launch_bounds__(SCAN_B) void k_scan3(int* __restrict__ rp16,
                                                  const int* __restrict__ bsum) {
  int i = blockIdx.x * SCAN_B + threadIdx.x;
  if (i < NN) rp16[i] += bsum[blockIdx.x];
}

// place pass: no atomics — slot came from k_count2
// colb stores BYTE offsets into the int8 msg array: src * 64
__global__ __launch_bounds__(256) void k_place(const int* __restrict__ src,
                                               const int* __restrict__ dst,
                                               const int* __restrict__ rp16,
                                               const int* __restrict__ pi,
                                               int* __restrict__ colb) {
  int i = blockIdx.x * 256 + threadIdx.x;
  if (i < NE) colb[rp16[dst[i]] + pi[i]] = src[i] * DH;  // 64 B rows
}

// ---------------- Encoder via MFMA: h = x @ W_enc + b_enc ----------------
__global__ __launch_bounds__(256) void k_enc_mfma(const float* __restrict__ x,
                                                  const float* __restrict__ W,
                                                  const float* __restrict__ b,
                                                  float* __restrict__ h) {
  __shared__ _Float16 Atile[4][2048];  // per-wave 16 x 128 f16 (256B rows)
  const int tid = threadIdx.x;
  const int w = tid >> 6, lane = tid & 63;
  const int gid = blockIdx.x * 4 + w;
  if (gid >= NGRP) return;  // no __syncthreads below
  const int row = lane & 15, hi = lane >> 4;

  v8h bf[4][4];
#pragma unroll
  for (int kt = 0; kt < 4; ++kt)
#pragma unroll
    for (int ct = 0; ct < 4; ++ct)
#pragma unroll
      for (int j = 0; j < 8; ++j)
        bf[kt][ct][j] = (_Float16)W[(kt * 32 + hi * 8 + j) * DH + ct * 16 + row];

  const int base = gid * 16;
  _Float16* At = &Atile[w][0];
#pragma unroll 4
  for (int i = 0; i < 16; ++i) {
    float v0 = x[(size_t)(base + i) * DIN + lane];
    float v1 = x[(size_t)(base + i) * DIN + 64 + lane];
    int swi = (i & 7) << 4;
    At[(i * 256 + ((lane * 2) ^ swi)) >> 1] = (_Float16)v0;
    At[(i * 256 + 128 + ((lane * 2) ^ swi)) >> 1] = (_Float16)v1;
  }
  const int sw = (row & 7) << 4;
  v8h a[4];
#pragma unroll
  for (int kt = 0; kt < 4; ++kt) {
    int off = (kt & 1) * 64 + hi * 16;
    a[kt] = *(const v8h*)&At[(row * 256 + (kt >> 1) * 128 + (off ^ sw)) >> 1];
  }
  v4f c0 = {0, 0, 0, 0}, c1 = {0, 0, 0, 0}, c2 = {0, 0, 0, 0}, c3 = {0, 0, 0, 0};
#pragma unroll
  for (int kt = 0; kt < 4; ++kt) {
    c0 = __builtin_amdgcn_mfma_f32_16x16x32_f16(a[kt], bf[kt][0], c0, 0, 0, 0);
    c1 = __builtin_amdgcn_mfma_f32_16x16x32_f16(a[kt], bf[kt][1], c1, 0, 0, 0);
    c2 = __builtin_amdgcn_mfma_f32_16x16x32_f16(a[kt], bf[kt][2], c2, 0, 0, 0);
    c3 = __builtin_amdgcn_mfma_f32_16x16x32_f16(a[kt], bf[kt][3], c3, 0, 0, 0);
  }
  float b0 = b[row], b1 = b[16 + row], b2 = b[32 + row], b3 = b[48 + row];
#pragma unroll
  for (int reg = 0; reg < 4; ++reg) {
    size_t o = (size_t)(base + hi * 4 + reg) * DH;
    h[o + row] = c0[reg] + b0;
    h[o + 16 + row] = c1[reg] + b1;
    h[o + 32 + row] = c2[reg] + b2;
    h[o + 48 + row] = c3[reg] + b3;
  }
}

// ---------------- Message precompute: msg = int8(clamp((relu(bn(h))+eps)*QS)) ----------------
__global__ __launch_bounds__(256) void k_msg(const float* __restrict__ h,
                                             const float* __restrict__ stats_in,
                                             const float* __restrict__ gamma,
                                             const float* __restrict__ beta,
                                             unsigned char* __restrict__ msg) {
  int lane = threadIdx.x & 63;
  float scale = 1.f, shift = 0.f;
  if (stats_in) {
    float mu = stats_in[lane] * (1.0f / NN);
    float var = stats_in[64 + lane] * (1.0f / NN) - mu * mu;
    scale = gamma[lane] * rsqrtf(var + 1e-5f);
    shift = beta[lane] - mu * scale;
  }
  int wid = (blockIdx.x * blockDim.x + threadIdx.x) >> 6;
  int nw = (gridDim.x * blockDim.x) >> 6;
  for (int n = wid; n < NN; n += nw) {
    float r = h[n * DH + lane];
    float v = fmaxf(fmaf(r, scale, shift), 0.f) + 1e-7f;
    msg[n * DH + lane] = (unsigned char)fminf(v * QS + 0.5f, 255.f);
  }
}

// ---------------- Gather + segment softmax agg: one wave per node ----------------
// int8 msg rows: 64B = ONE cache line per edge (64 lanes x 1B, coalesced).
__global__ __launch_bounds__(256, 8) void k_agg(const unsigned char* __restrict__ msg,
                                                const int* __restrict__ rp16,
                                                const int* __restrict__ cnt,
                                                const int* __restrict__ colb,
                                                _Float16* __restrict__ agg) {
  const int lane = threadIdx.x & 63;
  const int n = (blockIdx.x * 256 + threadIdx.x) >> 6;  // wave-uniform node
  const int beg = rp16[n];  // %16 == 0
  const int deg = cnt[n];
  const unsigned char* mb = msg + lane;
  float s = 0.f, t = 0.f;
  for (int j = 0; j < deg; j += 16) {
    int cc[16];
#pragma unroll
    for (int k = 0; k < 16; ++k) cc[k] = colb[beg + j + k];  // padded: safe
    float vv[16];
#pragma unroll
    for (int k = 0; k < 16; ++k) vv[k] = (float)mb[cc[k]] * IQS;
    int rem = deg - j;  // wave-uniform
#pragma unroll
    for (int k = 0; k < 16; ++k) {
      float e = (k < rem) ? __expf(vv[k]) : 0.f;
      s += e;
      t = fmaf(e, vv[k], t);
    }
  }
  agg[(size_t)n * DH + lane] = (_Float16)(t / (s + 1e-16f));
}

// ---------------- MFMA layer: combine(h,agg) -> GEMM (+bias,+res) ->
//                  per-block col-stat partials (NO atomics) ----------------
__global__ __launch_bounds__(256) void k_mfma(
    const float* __restrict__ h_pre, const _Float16* __restrict__ agg,
    const float* __restrict__ stats_in,
    const float* __restrict__ gamma, const float* __restrict__ beta,
    const float* __restrict__ W, const float* __restrict__ b, int add_res,
    float* __restrict__ hout, float* __restrict__ partial) {
  __shared__ _Float16 Atile[4][1024];  // per-wave swizzled 16x64 f16 A-tile
  const int tid = threadIdx.x;
  const int w = tid >> 6, lane = tid & 63;
  const int gid = blockIdx.x * 4 + w;
  const int row = lane & 15, hi = lane >> 4;

  float ss0 = 0, ss1 = 0, ss2 = 0, ss3 = 0;
  float qq0 = 0, qq1 = 0, qq2 = 0, qq3 = 0;

  if (gid < NGRP) {  // wave-uniform
    float scale = 1.f, shift = 0.f;
    if (stats_in) {
      float mu = stats_in[lane] * (1.0f / NN);
      float var = stats_in[64 + lane] * (1.0f / NN) - mu * mu;
      scale = gamma[lane] * rsqrtf(var + 1e-5f);
      shift = beta[lane] - mu * scale;
    }
    v8h bf[2][4];
#pragma unroll
    for (int kt = 0; kt < 2; ++kt)
#pragma unroll
      for (int ct = 0; ct < 4; ++ct)
#pragma unroll
        for (int j = 0; j < 8; ++j)
          bf[kt][ct][j] = (_Float16)W[(kt * 32 + hi * 8 + j) * DH + ct * 16 + row];

    const int base = gid * 16;
    const float* hl = h_pre + lane;
    const _Float16* agl = agg + lane;
    _Float16* At = &Atile[w][0];

    // ---- load phase: ALL independent loads issued up front ----
    float rawv[16], agv[16];
#pragma unroll
    for (int i = 0; i < 16; ++i) {
      size_t o = (size_t)(base + i) * DH;
      rawv[i] = hl[o];
      agv[i] = (float)agl[o];
    }
    float res[4][4];
    if (add_res) {
#pragma unroll
      for (int reg = 0; reg < 4; ++reg) {
        size_t o = (size_t)(base + hi * 4 + reg) * DH;
        res[reg][0] = h_pre[o + row];
        res[reg][1] = h_pre[o + 16 + row];
        res[reg][2] = h_pre[o + 32 + row];
        res[reg][3] = h_pre[o + 48 + row];
      }
    }
    // ---- convert + swizzled LDS write ----
#pragma unroll
    for (int i = 0; i < 16; ++i) {
      float v = stats_in ? fmaxf(fmaf(rawv[i], scale, shift), 0.f) : rawv[i];
      v += agv[i];
      At[(i * 128 + ((lane * 2) ^ ((i & 7) << 4))) >> 1] = (_Float16)v;
    }
    const int sw = (row & 7) << 4;
    v8h a0 = *(const v8h*)&At[((row * 128) + ((hi * 16) ^ sw)) >> 1];
    v8h a1 = *(const v8h*)&At[((row * 128) + ((64 + hi * 16) ^ sw)) >> 1];
    v4f c0 = {0, 0, 0, 0}, c1 = {0, 0, 0, 0}, c2 = {0, 0, 0, 0}, c3 = {0, 0, 0, 0};
    c0 = __builtin_amdgcn_mfma_f32_16x16x32_f16(a0, bf[0][0], c0, 0, 0, 0);
    c0 = __builtin_amdgcn_mfma_f32_16x16x32_f16(a1, bf[1][0], c0, 0, 0, 0);
    c1 = __builtin_amdgcn_mfma_f32_16x16x32_f16(a0, bf[0][1], c1, 0, 0, 0);
    c1 = __builtin_amdgcn_mfma_f32_16x16x32_f16(a1, bf[1][1], c1, 0, 0, 0);
    c2 = __builtin_amdgcn_mfma_f32_16x16x32_f16(a0, bf[0][2], c2, 0, 0, 0);
    c2 = __builtin_amdgcn_mfma_f32_16x16x32_f16(a1, bf[1][2], c2, 0, 0, 0);
    c3 = __builtin_amdgcn_mfma_f32_16x16x32_f16(a0, bf[0][3], c3, 0, 0, 0);
    c3 = __builtin_amdgcn_mfma_f32_16x16x32_f16(a1, bf[1][3], c3, 0, 0, 0);

    float b0 = b[row], b1 = b[16 + row], b2 = b[32 + row], b3 = b[48 + row];
#pragma unroll
    for (int reg = 0; reg < 4; ++reg) {
      size_t o = (size_t)(base + hi * 4 + reg) * DH;
      float a0v = c0[reg] + b0;
      float a1v = c1[reg] + b1;
      float a2v = c2[reg] + b2;
      float a3v = c3[reg] + b3;
      if (add_res) {
        a0v += res[reg][0];
        a1v += res[reg][1];
        a2v += res[reg][2];
        a3v += res[reg][3];
      }
      hout[o + row] = a0v;
      hout[o + 16 + row] = a1v;
      hout[o + 32 + row] = a2v;
      hout[o + 48 + row] = a3v;
      ss0 += a0v; qq0 = fmaf(a0v, a0v, qq0);
      ss1 += a1v; qq1 = fmaf(a1v, a1v, qq1);
      ss2 += a2v; qq2 = fmaf(a2v, a2v, qq2);
      ss3 += a3v; qq3 = fmaf(a3v, a3v, qq3);
    }
  }

  // reduce across the 4 row-groups (lanes l, l^16, l^32 share column)
#pragma unroll
  for (int off = 16; off <= 32; off <<= 1) {
    ss0 += __shfl_xor(ss0, off, 64); ss1 += __shfl_xor(ss1, off, 64);
    ss2 += __shfl_xor(ss2, off, 64); ss3 += __shfl_xor(ss3, off, 64);
    qq0 += __shfl_xor(qq0, off, 64); qq1 += __shfl_xor(qq1, off, 64);
    qq2 += __shfl_xor(qq2, off, 64); qq3 += __shfl_xor(qq3, off, 64);
  }
  __syncthreads();  // done with f16 A-tiles; reuse LDS as float scratch
  float* Sr = (float*)&Atile[0][0];
  if (lane < 16) {
    Sr[w * 128 + lane] = ss0;       Sr[w * 128 + 16 + lane] = ss1;
    Sr[w * 128 + 32 + lane] = ss2;  Sr[w * 128 + 48 + lane] = ss3;
    Sr[w * 128 + 64 + lane] = qq0;  Sr[w * 128 + 80 + lane] = qq1;
    Sr[w * 128 + 96 + lane] = qq2;  Sr[w * 128 + 112 + lane] = qq3;
  }
  __syncthreads();
  if (tid < 128) {
    float vsum = Sr[tid] + Sr[128 + tid] + Sr[256 + tid] + Sr[384 + tid];
    partial[(size_t)blockIdx.x * 128 + tid] = vsum;  // plain store, no atomic
  }
}

// ---------------- Partial-stats reduction: stats[f] = sum over blocks ----------------
__global__ __launch_bounds__(256) void k_red(const float* __restrict__ partial,
                                             float* __restrict__ stats) {
  const int f = blockIdx.x;  // 0..127
  float acc = 0.f;
  for (int i = threadIdx.x; i < LBLK; i += 256)
    acc += partial[(size_t)i * 128 + f];
  __shared__ float buf[256];
  buf[threadIdx.x] = acc;
  __syncthreads();
  for (int off = 128; off >= 1; off >>= 1) {
    if (threadIdx.x < off) buf[threadIdx.x] += buf[threadIdx.x + off];
    __syncthreads();
  }
  if (threadIdx.x == 0) stats[f] = buf[0];
}

// ---------------- Prediction via MFMA: BN+ReLU -> @W_pred+b -> log_softmax ----
__global__ __launch_bounds__(256) void k_pred_mfma(
    const float* __restrict__ h_pre, const float* __restrict__ stats_in,
    const float* __restrict__ gamma, const float* __restrict__ beta,
    const float* __restrict__ Wp, const float* __restrict__ bp,
    float* __restrict__ out) {
  __shared__ _Float16 Atile[4][1024];
  const int tid = threadIdx.x;
  const int w = tid >> 6, lane = tid & 63;
  const int gid = blockIdx.x * 4 + w;
  if (gid >= NGRP) return;  // no __syncthreads below
  const int row = lane & 15, hi = lane >> 4;

  float mu = stats_in[lane] * (1.0f / NN);
  float var = stats_in[64 + lane] * (1.0f / NN) - mu * mu;
  float scale = gamma[lane] * rsqrtf(var + 1e-5f);
  float shift = beta[lane] - mu * scale;

  v8h bf[2][3];
#pragma unroll
  for (int kt = 0; kt < 2; ++kt)
#pragma unroll
    for (int ct = 0; ct < 3; ++ct) {
      int n = ct * 16 + row;
#pragma unroll
      for (int j = 0; j < 8; ++j)
        bf[kt][ct][j] =
            (n < DOUT) ? (_Float16)Wp[(kt * 32 + hi * 8 + j) * DOUT + n]
                       : (_Float16)0.f;
    }

  const int base = gid * 16;
  const float* hl = h_pre + lane;
  _Float16* At = &Atile[w][0];
#pragma unroll 4
  for (int i = 0; i < 16; ++i) {
    float raw = hl[(size_t)(base + i) * DH];
    float v = fmaxf(fmaf(raw, scale, shift), 0.f);
    At[(i * 128 + ((lane * 2) ^ ((i & 7) << 4))) >> 1] = (_Float16)v;
  }
  const int sw = (row & 7) << 4;
  v8h a0 = *(const v8h*)&At[((row * 128) + ((hi * 16) ^ sw)) >> 1];
  v8h a1 = *(const v8h*)&At[((row * 128) + ((64 + hi * 16) ^ sw)) >> 1];
  v4f c0 = {0, 0, 0, 0}, c1 = {0, 0, 0, 0}, c2 = {0, 0, 0, 0};
  c0 = __builtin_amdgcn_mfma_f32_16x16x32_f16(a0, bf[0][0], c0, 0, 0, 0);
  c0 = __builtin_amdgcn_mfma_f32_16x16x32_f16(a1, bf[1][0], c0, 0, 0, 0);
  c1 = __builtin_amdgcn_mfma_f32_16x16x32_f16(a0, bf[0][1], c1, 0, 0, 0);
  c1 = __builtin_amdgcn_mfma_f32_16x16x32_f16(a1, bf[1][1], c1, 0, 0, 0);
  c2 = __builtin_amdgcn_mfma_f32_16x16x32_f16(a0, bf[0][2], c2, 0, 0, 0);
  c2 = __builtin_amdgcn_mfma_f32_16x16x32_f16(a1, bf[1][2], c2, 0, 0, 0);

  float bp0 = bp[row], bp1 = bp[16 + row];
  float bp2 = (32 + row < DOUT) ? bp[32 + row] : 0.f;
  bool v2 = (32 + row) < DOUT;
#pragma unroll
  for (int reg = 0; reg < 4; ++reg) {
    float l0 = c0[reg] + bp0;
    float l1 = c1[reg] + bp1;
    float l2 = v2 ? (c2[reg] + bp2) : -INFINITY;
    float xm = fmaxf(fmaxf(l0, l1), l2);
#pragma unroll
    for (int off = 1; off <= 8; off <<= 1) xm = fmaxf(xm, __shfl_xor(xm, off, 64));
    float e = __expf(l0 - xm) + __expf(l1 - xm) + (v2 ? __expf(l2 - xm) : 0.f);
#pragma unroll
    for (int off = 1; off <= 8; off <<= 1) e += __shfl_xor(e, off, 64);
    float ls = xm + __logf(e);
    size_t o = (size_t)(base + hi * 4 + reg) * DOUT;
    out[o + row] = l0 - ls;
    out[o + 16 + row] = l1 - ls;
    if (v2) out[o + 32 + row] = l2 - ls;
  }
}

extern "C" void kernel_launch(void* const* d_in, const int* in_sizes, int n_in,
                              void* d_out, int out_size, void* d_ws, size_t ws_size,
                              hipStream_t stream) {
  const float* x      = (const float*)d_in[0];
  const int*   ei     = (const int*)d_in[1];
  const float* W_enc  = (const float*)d_in[2];
  const float* b_enc  = (const float*)d_in[3];
  const float* Wg     = (const float*)d_in[4];
  const float* bg     = (const float*)d_in[5];
  const float* gamma  = (const float*)d_in[6];
  const float* beta   = (const float*)d_in[7];
  const float* W_pred = (const float*)d_in[8];
  const float* b_pred = (const float*)d_in[9];
  float* out = (float*)d_out;

  const int* src = ei;
  const int* dst = ei + NE;

  char* p = (char*)d_ws;
  auto alloc = [&](size_t bytes) -> void* {
    void* r = (void*)p;
    p += (bytes + 255) & ~(size_t)255;
    return r;
  };
  float*         hA      = (float*)alloc((size_t)NN * DH * 4);
  float*         hB      = (float*)alloc((size_t)NN * DH * 4);
  unsigned char* msg     = (unsigned char*)alloc((size_t)NN * DH);
  _Float16*      agg     = (_Float16*)alloc((size_t)NN * DH * 2);
  int*           rp16    = (int*)alloc((size_t)(NN + 1) * 4);
  int*           pi      = (int*)alloc((size_t)NE * 4);
  int*           cnt     = (int*)alloc((size_t)NN * 4);
  int*           colb    = (int*)alloc((size_t)COLB_CAP * 4);
  int*           bsum    = (int*)alloc((size_t)NBLK * 4);
  float*         stats   = (float*)alloc((size_t)NL * 128 * 4);
  float*         partial = (float*)alloc((size_t)LBLK * 128 * 4);

  hipMemsetAsync(cnt, 0, (size_t)NN * 4, stream);
  hipMemsetAsync(colb, 0, (size_t)COLB_CAP * 4, stream);  // pads -> row 0 (masked)

  // ---- CSR build (16-padded segments; slot-memo, no atomic in place pass) ----
  k_count2<<<(NE + 255) / 256, 256, 0, stream>>>(dst, cnt, pi);
  k_scan1<<<NBLK, SCAN_B, 0, stream>>>(cnt, rp16, bsum);
  k_scan2<<<1, 128, 0, stream>>>(bsum);
  k_scan3<<<NBLK, SCAN_B, 0, stream>>>(rp16, bsum);
  k_place<<<(NE + 255) / 256, 256, 0, stream>>>(src, dst, rp16, pi, colb);

  // ---- Encoder (MFMA) ----
  k_enc_mfma<<<LBLK, 256, 0, stream>>>(x, W_enc, b_enc, hA);

  const int MSG_BLOCKS = 1024;
  const int AGG_BLOCKS = NN * 64 / 256;  // one wave per node

  // ---- Layer 0 (no BN; combine uses raw h; msg = relu(h)+eps) ----
  k_msg<<<MSG_BLOCKS, 256, 0, stream>>>(hA, nullptr, nullptr, nullptr, msg);
  k_agg<<<AGG_BLOCKS, 256, 0, stream>>>(msg, rp16, cnt, colb, agg);
  k_mfma<<<LBLK, 256, 0, stream>>>(
      hA, agg, nullptr, nullptr, nullptr, Wg, bg, 0, hB, partial);
  k_red<<<128, 256, 0, stream>>>(partial, stats);

  float* h = hB;
  float* hn = hA;
  for (int l = 1; l < NL; ++l) {
    const float* st = stats + (size_t)(l - 1) * 128;
    const float* g  = gamma + (size_t)(l - 1) * DH;
    const float* be = beta + (size_t)(l - 1) * DH;
    k_msg<<<MSG_BLOCKS, 256, 0, stream>>>(h, st, g, be, msg);
    k_agg<<<AGG_BLOCKS, 256, 0, stream>>>(msg, rp16, cnt, colb, agg);
    k_mfma<<<LBLK, 256, 0, stream>>>(
        h, agg, st, g, be,
        Wg + (size_t)l * DH * DH, bg + (size_t)l * DH, 1,
        hn, partial);
    k_red<<<128, 256, 0, stream>>>(partial, stats + (size_t)l * 128);
    float* tmp = h; h = hn; hn = tmp;
  }

  // ---- Final BN + ReLU + prediction + log_softmax (MFMA) ----
  k_pred_mfma<<<LBLK, 256, 0, stream>>>(
      h, stats + (size_t)(NL - 1) * 128,
      gamma + (size_t)(NL - 1) * DH, beta + (size_t)(NL - 1) * DH,
      W_pred, b_pred, out);
}

// Round 15
// 517.470 us; speedup vs baseline: 1.9094x; 1.0707x over previous
//
#include <hip/hip_runtime.h>
#include <math.h>

#define NN 100000
#define NE 1000000
#define DH 64
#define DIN 128
#define DOUT 40
#define NL 7
#define SCAN_B 1024
#define NBLK ((NN + SCAN_B - 1) / SCAN_B)  // 98
#define NGRP (NN / 16)     // 6250 16-node groups (exact)
#define LBLK ((NGRP + 3) / 4)              // 1563 blocks for MFMA kernels
#define COLB_CAP (NE + 8 * NN + 64)  // pad-8 CSR capacity (entries)
#define QS 16.0f           // int8 quant scale: q = round(v*QS), v' = q/QS
#define IQS 0.0625f

typedef _Float16 v8h __attribute__((ext_vector_type(8)));
typedef float v4f __attribute__((ext_vector_type(4)));

// ---------------- CSR build: 4-sharded count (slot-memo), pad-8 scan, place ----------------
__global__ __launch_bounds__(256) void k_count4(const int* __restrict__ dst,
                                                int* __restrict__ cnt4,
                                                int* __restrict__ pi) {
  int i = blockIdx.x * 256 + threadIdx.x;
  if (i < NE) pi[i] = atomicAdd(&cnt4[(size_t)(i & 3) * NN + dst[i]], 1);
}

// exclusive scan over PADDED totals: ceil8(sum of 4 shards); emit per-shard bases
__global__ __launch_bounds__(SCAN_B) void k_scan1(const int* __restrict__ cnt4,
                                                  int* __restrict__ cnt,
                                                  int* __restrict__ rp8,
                                                  int* __restrict__ rp8s,
                                                  int* __restrict__ bsum) {
  __shared__ int buf[SCAN_B];
  int i = blockIdx.x * SCAN_B + threadIdx.x;
  int c0 = 0, c1 = 0, c2 = 0, c3 = 0;
  if (i < NN) {
    c0 = cnt4[i];
    c1 = cnt4[(size_t)NN + i];
    c2 = cnt4[(size_t)2 * NN + i];
    c3 = cnt4[(size_t)3 * NN + i];
  }
  int tot = c0 + c1 + c2 + c3;
  int t8 = (tot + 7) & ~7;
  buf[threadIdx.x] = t8;
  __syncthreads();
  for (int off = 1; off < SCAN_B; off <<= 1) {
    int t = (threadIdx.x >= off) ? buf[threadIdx.x - off] : 0;
    __syncthreads();
    buf[threadIdx.x] += t;
    __syncthreads();
  }
  if (i < NN) {
    int excl = buf[threadIdx.x] - t8;  // block-local exclusive
    cnt[i] = tot;
    rp8[i] = excl;
    rp8s[4 * i] = excl;
    rp8s[4 * i + 1] = excl + c0;
    rp8s[4 * i + 2] = excl + c0 + c1;
    rp8s[4 * i + 3] = excl + c0 + c1 + c2;
  }
  if (threadIdx.x == SCAN_B - 1) bsum[blockIdx.x] = buf[SCAN_B - 1];
}

__global__ __launch_bounds__(128) void k_scan2(int* __restrict__ bsum) {
  __shared__ int buf[128];
  int v = (threadIdx.x < NBLK) ? bsum[threadIdx.x] : 0;
  buf[threadIdx.x] = v;
  __syncthreads();
  for (int off = 1; off < 128; off <<= 1) {
    int t = (threadIdx.x >= off) ? buf[threadIdx.x - off] : 0;
    __syncthreads();
    buf[threadIdx.x] += t;
    __syncthreads();
  }
  if (threadIdx.x < NBLK) bsum[threadIdx.x] = buf[threadIdx.x] - v;
}

__global__ __launch_bounds__(SCAN_B) void k_scan3(int* __restrict__ rp8,
                                                  int* __restrict__ rp8s,
                                                  const int* __restrict__ bsum) {
  int i = blockIdx.x * SCAN_B + threadIdx.x;
  if (i < NN) {
    int b = bsum[blockIdx.x];
    rp8[i] += b;
    rp8s[4 * i] += b;
    rp8s[4 * i + 1] += b;
    rp8s[4 * i + 2] += b;
    rp8s[4 * i + 3] += b;
  }
}

// place pass: no atomics — slot = shard base + memoized shard-local index
// colb stores BYTE offsets into msg (+64: row 0 is the zero row for pads)
__global__ __launch_bounds__(256) void k_place(const int* __restrict__ src,
                                               const int* __restrict__ dst,
                                               const int* __restrict__ rp8s,
                                               const int* __restrict__ pi,
                                               int* __restrict__ colb) {
  int i = blockIdx.x * 256 + threadIdx.x;
  if (i < NE)
    colb[rp8s[4 * dst[i] + (i & 3)] + pi[i]] = src[i] * DH + DH;
}

// ---------------- Encoder via MFMA: h = x @ W_enc + b_enc ----------------
__global__ __launch_bounds__(256) void k_enc_mfma(const float* __restrict__ x,
                                                  const float* __restrict__ W,
                                                  const float* __restrict__ b,
                                                  float* __restrict__ h) {
  __shared__ _Float16 Atile[4][2048];  // per-wave 16 x 128 f16 (256B rows)
  const int tid = threadIdx.x;
  const int w = tid >> 6, lane = tid & 63;
  const int gid = blockIdx.x * 4 + w;
  if (gid >= NGRP) return;  // no __syncthreads below
  const int row = lane & 15, hi = lane >> 4;

  v8h bf[4][4];
#pragma unroll
  for (int kt = 0; kt < 4; ++kt)
#pragma unroll
    for (int ct = 0; ct < 4; ++ct)
#pragma unroll
      for (int j = 0; j < 8; ++j)
        bf[kt][ct][j] = (_Float16)W[(kt * 32 + hi * 8 + j) * DH + ct * 16 + row];

  const int base = gid * 16;
  _Float16* At = &Atile[w][0];
#pragma unroll 4
  for (int i = 0; i < 16; ++i) {
    float v0 = x[(size_t)(base + i) * DIN + lane];
    float v1 = x[(size_t)(base + i) * DIN + 64 + lane];
    int swi = (i & 7) << 4;
    At[(i * 256 + ((lane * 2) ^ swi)) >> 1] = (_Float16)v0;
    At[(i * 256 + 128 + ((lane * 2) ^ swi)) >> 1] = (_Float16)v1;
  }
  const int sw = (row & 7) << 4;
  v8h a[4];
#pragma unroll
  for (int kt = 0; kt < 4; ++kt) {
    int off = (kt & 1) * 64 + hi * 16;
    a[kt] = *(const v8h*)&At[(row * 256 + (kt >> 1) * 128 + (off ^ sw)) >> 1];
  }
  v4f c0 = {0, 0, 0, 0}, c1 = {0, 0, 0, 0}, c2 = {0, 0, 0, 0}, c3 = {0, 0, 0, 0};
#pragma unroll
  for (int kt = 0; kt < 4; ++kt) {
    c0 = __builtin_amdgcn_mfma_f32_16x16x32_f16(a[kt], bf[kt][0], c0, 0, 0, 0);
    c1 = __builtin_amdgcn_mfma_f32_16x16x32_f16(a[kt], bf[kt][1], c1, 0, 0, 0);
    c2 = __builtin_amdgcn_mfma_f32_16x16x32_f16(a[kt], bf[kt][2], c2, 0, 0, 0);
    c3 = __builtin_amdgcn_mfma_f32_16x16x32_f16(a[kt], bf[kt][3], c3, 0, 0, 0);
  }
  float b0 = b[row], b1 = b[16 + row], b2 = b[32 + row], b3 = b[48 + row];
#pragma unroll
  for (int reg = 0; reg < 4; ++reg) {
    size_t o = (size_t)(base + hi * 4 + reg) * DH;
    h[o + row] = c0[reg] + b0;
    h[o + 16 + row] = c1[reg] + b1;
    h[o + 32 + row] = c2[reg] + b2;
    h[o + 48 + row] = c3[reg] + b3;
  }
}

// ---------------- Message precompute: msg row n+1 = int8((relu(bn(h))+eps)*QS) ----------------
// Row 0 of msg is the zero row (pads read it: q=0 -> e=1, subtracted exactly).
__global__ __launch_bounds__(256) void k_msg(const float* __restrict__ h,
                                             const float* __restrict__ stats_in,
                                             const float* __restrict__ gamma,
                                             const float* __restrict__ beta,
                                             unsigned char* __restrict__ msg) {
  int lane = threadIdx.x & 63;
  float scale = 1.f, shift = 0.f;
  if (stats_in) {
    float mu = stats_in[lane] * (1.0f / NN);
    float var = stats_in[64 + lane] * (1.0f / NN) - mu * mu;
    scale = gamma[lane] * rsqrtf(var + 1e-5f);
    shift = beta[lane] - mu * scale;
  }
  int wid = (blockIdx.x * blockDim.x + threadIdx.x) >> 6;
  int nw = (gridDim.x * blockDim.x) >> 6;
  for (int n = wid; n < NN; n += nw) {
    float r = h[n * DH + lane];
    float v = fmaxf(fmaf(r, scale, shift), 0.f) + 1e-7f;
    msg[DH + n * DH + lane] = (unsigned char)fminf(v * QS + 0.5f, 255.f);
  }
}

// ---------------- Gather + segment softmax agg: one wave per node ----------------
// pad-8 CSR, zero-row pads (no per-edge mask), scalarized col indices.
__global__ __launch_bounds__(256, 8) void k_agg(const unsigned char* __restrict__ msg,
                                                const int* __restrict__ rp8,
                                                const int* __restrict__ cnt,
                                                const int* __restrict__ colb,
                                                _Float16* __restrict__ agg) {
  const int lane = threadIdx.x & 63;
  const int n = (blockIdx.x * 256 + threadIdx.x) >> 6;  // wave-uniform node
  const int beg = __builtin_amdgcn_readfirstlane(rp8[n]);   // %8 == 0
  const int deg = __builtin_amdgcn_readfirstlane(cnt[n]);
  const int pdeg = (deg + 7) & ~7;
  const unsigned char* mb = msg + lane;
  float s = 0.f, t = 0.f;
  for (int j = 0; j < pdeg; j += 8) {
    int cc[8];
#pragma unroll
    for (int k = 0; k < 8; ++k) cc[k] = colb[beg + j + k];  // uniform -> s_load
    float vv[8];
#pragma unroll
    for (int k = 0; k < 8; ++k) vv[k] = (float)mb[cc[k]] * IQS;
#pragma unroll
    for (int k = 0; k < 8; ++k) {
      float e = __expf(vv[k]);  // pads: exp(0)=1, subtracted below
      s += e;
      t = fmaf(e, vv[k], t);
    }
  }
  s -= (float)(pdeg - deg);
  agg[(size_t)n * DH + lane] = (_Float16)(t / (s + 1e-16f));
}

// ---------------- MFMA layer: combine(h,agg) -> GEMM (+bias,+res) ->
//                  per-block col-stat partials (NO atomics) ----------------
__global__ __launch_bounds__(256) void k_mfma(
    const float* __restrict__ h_pre, const _Float16* __restrict__ agg,
    const float* __restrict__ stats_in,
    const float* __restrict__ gamma, const float* __restrict__ beta,
    const float* __restrict__ W, const float* __restrict__ b, int add_res,
    float* __restrict__ hout, float* __restrict__ partial) {
  __shared__ _Float16 Atile[4][1024];  // per-wave swizzled 16x64 f16 A-tile
  const int tid = threadIdx.x;
  const int w = tid >> 6, lane = tid & 63;
  const int gid = blockIdx.x * 4 + w;
  const int row = lane & 15, hi = lane >> 4;

  float ss0 = 0, ss1 = 0, ss2 = 0, ss3 = 0;
  float qq0 = 0, qq1 = 0, qq2 = 0, qq3 = 0;

  if (gid < NGRP) {  // wave-uniform
    float scale = 1.f, shift = 0.f;
    if (stats_in) {
      float mu = stats_in[lane] * (1.0f / NN);
      float var = stats_in[64 + lane] * (1.0f / NN) - mu * mu;
      scale = gamma[lane] * rsqrtf(var + 1e-5f);
      shift = beta[lane] - mu * scale;
    }
    v8h bf[2][4];
#pragma unroll
    for (int kt = 0; kt < 2; ++kt)
#pragma unroll
      for (int ct = 0; ct < 4; ++ct)
#pragma unroll
        for (int j = 0; j < 8; ++j)
          bf[kt][ct][j] = (_Float16)W[(kt * 32 + hi * 8 + j) * DH + ct * 16 + row];

    const int base = gid * 16;
    const float* hl = h_pre + lane;
    const _Float16* agl = agg + lane;
    _Float16* At = &Atile[w][0];

    // ---- load phase: ALL independent loads issued up front ----
    float rawv[16], agv[16];
#pragma unroll
    for (int i = 0; i < 16; ++i) {
      size_t o = (size_t)(base + i) * DH;
      rawv[i] = hl[o];
      agv[i] = (float)agl[o];
    }
    float res[4][4];
    if (add_res) {
#pragma unroll
      for (int reg = 0; reg < 4; ++reg) {
        size_t o = (size_t)(base + hi * 4 + reg) * DH;
        res[reg][0] = h_pre[o + row];
        res[reg][1] = h_pre[o + 16 + row];
        res[reg][2] = h_pre[o + 32 + row];
        res[reg][3] = h_pre[o + 48 + row];
      }
    }
    // ---- convert + swizzled LDS write ----
#pragma unroll
    for (int i = 0; i < 16; ++i) {
      float v = stats_in ? fmaxf(fmaf(rawv[i], scale, shift), 0.f) : rawv[i];
      v += agv[i];
      At[(i * 128 + ((lane * 2) ^ ((i & 7) << 4))) >> 1] = (_Float16)v;
    }
    const int sw = (row & 7) << 4;
    v8h a0 = *(const v8h*)&At[((row * 128) + ((hi * 16) ^ sw)) >> 1];
    v8h a1 = *(const v8h*)&At[((row * 128) + ((64 + hi * 16) ^ sw)) >> 1];
    v4f c0 = {0, 0, 0, 0}, c1 = {0, 0, 0, 0}, c2 = {0, 0, 0, 0}, c3 = {0, 0, 0, 0};
    c0 = __builtin_amdgcn_mfma_f32_16x16x32_f16(a0, bf[0][0], c0, 0, 0, 0);
    c0 = __builtin_amdgcn_mfma_f32_16x16x32_f16(a1, bf[1][0], c0, 0, 0, 0);
    c1 = __builtin_amdgcn_mfma_f32_16x16x32_f16(a0, bf[0][1], c1, 0, 0, 0);
    c1 = __builtin_amdgcn_mfma_f32_16x16x32_f16(a1, bf[1][1], c1, 0, 0, 0);
    c2 = __builtin_amdgcn_mfma_f32_16x16x32_f16(a0, bf[0][2], c2, 0, 0, 0);
    c2 = __builtin_amdgcn_mfma_f32_16x16x32_f16(a1, bf[1][2], c2, 0, 0, 0);
    c3 = __builtin_amdgcn_mfma_f32_16x16x32_f16(a0, bf[0][3], c3, 0, 0, 0);
    c3 = __builtin_amdgcn_mfma_f32_16x16x32_f16(a1, bf[1][3], c3, 0, 0, 0);

    float b0 = b[row], b1 = b[16 + row], b2 = b[32 + row], b3 = b[48 + row];
#pragma unroll
    for (int reg = 0; reg < 4; ++reg) {
      size_t o = (size_t)(base + hi * 4 + reg) * DH;
      float a0v = c0[reg] + b0;
      float a1v = c1[reg] + b1;
      float a2v = c2[reg] + b2;
      float a3v = c3[reg] + b3;
      if (add_res) {
        a0v += res[reg][0];
        a1v += res[reg][1];
        a2v += res[reg][2];
        a3v += res[reg][3];
      }
      hout[o + row] = a0v;
      hout[o + 16 + row] = a1v;
      hout[o + 32 + row] = a2v;
      hout[o + 48 + row] = a3v;
      ss0 += a0v; qq0 = fmaf(a0v, a0v, qq0);
      ss1 += a1v; qq1 = fmaf(a1v, a1v, qq1);
      ss2 += a2v; qq2 = fmaf(a2v, a2v, qq2);
      ss3 += a3v; qq3 = fmaf(a3v, a3v, qq3);
    }
  }

  // reduce across the 4 row-groups (lanes l, l^16, l^32 share column)
#pragma unroll
  for (int off = 16; off <= 32; off <<= 1) {
    ss0 += __shfl_xor(ss0, off, 64); ss1 += __shfl_xor(ss1, off, 64);
    ss2 += __shfl_xor(ss2, off, 64); ss3 += __shfl_xor(ss3, off, 64);
    qq0 += __shfl_xor(qq0, off, 64); qq1 += __shfl_xor(qq1, off, 64);
    qq2 += __shfl_xor(qq2, off, 64); qq3 += __shfl_xor(qq3, off, 64);
  }
  __syncthreads();  // done with f16 A-tiles; reuse LDS as float scratch
  float* Sr = (float*)&Atile[0][0];
  if (lane < 16) {
    Sr[w * 128 + lane] = ss0;       Sr[w * 128 + 16 + lane] = ss1;
    Sr[w * 128 + 32 + lane] = ss2;  Sr[w * 128 + 48 + lane] = ss3;
    Sr[w * 128 + 64 + lane] = qq0;  Sr[w * 128 + 80 + lane] = qq1;
    Sr[w * 128 + 96 + lane] = qq2;  Sr[w * 128 + 112 + lane] = qq3;
  }
  __syncthreads();
  if (tid < 128) {
    float vsum = Sr[tid] + Sr[128 + tid] + Sr[256 + tid] + Sr[384 + tid];
    partial[(size_t)blockIdx.x * 128 + tid] = vsum;  // plain store, no atomic
  }
}

// ---------------- Partial-stats reduction: stats[f] = sum over blocks ----------------
__global__ __launch_bounds__(256) void k_red(const float* __restrict__ partial,
                                             float* __restrict__ stats) {
  const int f = blockIdx.x;  // 0..127
  float acc = 0.f;
  for (int i = threadIdx.x; i < LBLK; i += 256)
    acc += partial[(size_t)i * 128 + f];
  __shared__ float buf[256];
  buf[threadIdx.x] = acc;
  __syncthreads();
  for (int off = 128; off >= 1; off >>= 1) {
    if (threadIdx.x < off) buf[threadIdx.x] += buf[threadIdx.x + off];
    __syncthreads();
  }
  if (threadIdx.x == 0) stats[f] = buf[0];
}

// ---------------- Prediction via MFMA: BN+ReLU -> @W_pred+b -> log_softmax ----
__global__ __launch_bounds__(256) void k_pred_mfma(
    const float* __restrict__ h_pre, const float* __restrict__ stats_in,
    const float* __restrict__ gamma, const float* __restrict__ beta,
    const float* __restrict__ Wp, const float* __restrict__ bp,
    float* __restrict__ out) {
  __shared__ _Float16 Atile[4][1024];
  const int tid = threadIdx.x;
  const int w = tid >> 6, lane = tid & 63;
  const int gid = blockIdx.x * 4 + w;
  if (gid >= NGRP) return;  // no __syncthreads below
  const int row = lane & 15, hi = lane >> 4;

  float mu = stats_in[lane] * (1.0f / NN);
  float var = stats_in[64 + lane] * (1.0f / NN) - mu * mu;
  float scale = gamma[lane] * rsqrtf(var + 1e-5f);
  float shift = beta[lane] - mu * scale;

  v8h bf[2][3];
#pragma unroll
  for (int kt = 0; kt < 2; ++kt)
#pragma unroll
    for (int ct = 0; ct < 3; ++ct) {
      int n = ct * 16 + row;
#pragma unroll
      for (int j = 0; j < 8; ++j)
        bf[kt][ct][j] =
            (n < DOUT) ? (_Float16)Wp[(kt * 32 + hi * 8 + j) * DOUT + n]
                       : (_Float16)0.f;
    }

  const int base = gid * 16;
  const float* hl = h_pre + lane;
  _Float16* At = &Atile[w][0];
#pragma unroll 4
  for (int i = 0; i < 16; ++i) {
    float raw = hl[(size_t)(base + i) * DH];
    float v = fmaxf(fmaf(raw, scale, shift), 0.f);
    At[(i * 128 + ((lane * 2) ^ ((i & 7) << 4))) >> 1] = (_Float16)v;
  }
  const int sw = (row & 7) << 4;
  v8h a0 = *(const v8h*)&At[((row * 128) + ((hi * 16) ^ sw)) >> 1];
  v8h a1 = *(const v8h*)&At[((row * 128) + ((64 + hi * 16) ^ sw)) >> 1];
  v4f c0 = {0, 0, 0, 0}, c1 = {0, 0, 0, 0}, c2 = {0, 0, 0, 0};
  c0 = __builtin_amdgcn_mfma_f32_16x16x32_f16(a0, bf[0][0], c0, 0, 0, 0);
  c0 = __builtin_amdgcn_mfma_f32_16x16x32_f16(a1, bf[1][0], c0, 0, 0, 0);
  c1 = __builtin_amdgcn_mfma_f32_16x16x32_f16(a0, bf[0][1], c1, 0, 0, 0);
  c1 = __builtin_amdgcn_mfma_f32_16x16x32_f16(a1, bf[1][1], c1, 0, 0, 0);
  c2 = __builtin_amdgcn_mfma_f32_16x16x32_f16(a0, bf[0][2], c2, 0, 0, 0);
  c2 = __builtin_amdgcn_mfma_f32_16x16x32_f16(a1, bf[1][2], c2, 0, 0, 0);

  float bp0 = bp[row], bp1 = bp[16 + row];
  float bp2 = (32 + row < DOUT) ? bp[32 + row] : 0.f;
  bool v2 = (32 + row) < DOUT;
#pragma unroll
  for (int reg = 0; reg < 4; ++reg) {
    float l0 = c0[reg] + bp0;
    float l1 = c1[reg] + bp1;
    float l2 = v2 ? (c2[reg] + bp2) : -INFINITY;
    float xm = fmaxf(fmaxf(l0, l1), l2);
#pragma unroll
    for (int off = 1; off <= 8; off <<= 1) xm = fmaxf(xm, __shfl_xor(xm, off, 64));
    float e = __expf(l0 - xm) + __expf(l1 - xm) + (v2 ? __expf(l2 - xm) : 0.f);
#pragma unroll
    for (int off = 1; off <= 8; off <<= 1) e += __shfl_xor(e, off, 64);
    float ls = xm + __logf(e);
    size_t o = (size_t)(base + hi * 4 + reg) * DOUT;
    out[o + row] = l0 - ls;
    out[o + 16 + row] = l1 - ls;
    if (v2) out[o + 32 + row] = l2 - ls;
  }
}

extern "C" void kernel_launch(void* const* d_in, const int* in_sizes, int n_in,
                              void* d_out, int out_size, void* d_ws, size_t ws_size,
                              hipStream_t stream) {
  const float* x      = (const float*)d_in[0];
  const int*   ei     = (const int*)d_in[1];
  const float* W_enc  = (const float*)d_in[2];
  const float* b_enc  = (const float*)d_in[3];
  const float* Wg     = (const float*)d_in[4];
  const float* bg     = (const float*)d_in[5];
  const float* gamma  = (const float*)d_in[6];
  const float* beta   = (const float*)d_in[7];
  const float* W_pred = (const float*)d_in[8];
  const float* b_pred = (const float*)d_in[9];
  float* out = (float*)d_out;

  const int* src = ei;
  const int* dst = ei + NE;

  char* p = (char*)d_ws;
  auto alloc = [&](size_t bytes) -> void* {
    void* r = (void*)p;
    p += (bytes + 255) & ~(size_t)255;
    return r;
  };
  float*         hA      = (float*)alloc((size_t)NN * DH * 4);
  float*         hB      = (float*)alloc((size_t)NN * DH * 4);
  unsigned char* msg     = (unsigned char*)alloc((size_t)(NN + 1) * DH);  // row 0 = zero row
  _Float16*      agg     = (_Float16*)alloc((size_t)NN * DH * 2);
  int*           rp8     = (int*)alloc((size_t)NN * 4);
  int*           rp8s    = (int*)alloc((size_t)NN * 4 * 4);
  int*           pi      = (int*)alloc((size_t)NE * 4);
  int*           cnt     = (int*)alloc((size_t)NN * 4);
  int*           cnt4    = (int*)alloc((size_t)NN * 4 * 4);
  int*           colb    = (int*)alloc((size_t)COLB_CAP * 4);
  int*           bsum    = (int*)alloc((size_t)NBLK * 4);
  float*         stats   = (float*)alloc((size_t)NL * 128 * 4);
  float*         partial = (float*)alloc((size_t)LBLK * 128 * 4);

  hipMemsetAsync(cnt4, 0, (size_t)NN * 16, stream);
  hipMemsetAsync(colb, 0, (size_t)COLB_CAP * 4, stream);  // pads -> zero row
  hipMemsetAsync(msg, 0, DH, stream);                      // zero row

  // ---- CSR build (pad-8; 4-sharded count; atomic-free place) ----
  k_count4<<<(NE + 255) / 256, 256, 0, stream>>>(dst, cnt4, pi);
  k_scan1<<<NBLK, SCAN_B, 0, stream>>>(cnt4, cnt, rp8, rp8s, bsum);
  k_scan2<<<1, 128, 0, stream>>>(bsum);
  k_scan3<<<NBLK, SCAN_B, 0, stream>>>(rp8, rp8s, bsum);
  k_place<<<(NE + 255) / 256, 256, 0, stream>>>(src, dst, rp8s, pi, colb);

  // ---- Encoder (MFMA) ----
  k_enc_mfma<<<LBLK, 256, 0, stream>>>(x, W_enc, b_enc, hA);

  const int MSG_BLOCKS = 1024;
  const int AGG_BLOCKS = NN * 64 / 256;  // one wave per node

  // ---- Layer 0 (no BN; combine uses raw h; msg = relu(h)+eps) ----
  k_msg<<<MSG_BLOCKS, 256, 0, stream>>>(hA, nullptr, nullptr, nullptr, msg);
  k_agg<<<AGG_BLOCKS, 256, 0, stream>>>(msg, rp8, cnt, colb, agg);
  k_mfma<<<LBLK, 256, 0, stream>>>(
      hA, agg, nullptr, nullptr, nullptr, Wg, bg, 0, hB, partial);
  k_red<<<128, 256, 0, stream>>>(partial, stats);

  float* h = hB;
  float* hn = hA;
  for (int l = 1; l < NL; ++l) {
    const float* st = stats + (size_t)(l - 1) * 128;
    const float* g  = gamma + (size_t)(l - 1) * DH;
    const float* be = beta + (size_t)(l - 1) * DH;
    k_msg<<<MSG_BLOCKS, 256, 0, stream>>>(h, st, g, be, msg);
    k_agg<<<AGG_BLOCKS, 256, 0, stream>>>(msg, rp8, cnt, colb, agg);
    k_mfma<<<LBLK, 256, 0, stream>>>(
        h, agg, st, g, be,
        Wg + (size_t)l * DH * DH, bg + (size_t)l * DH, 1,
        hn, partial);
    k_red<<<128, 256, 0, stream>>>(partial, stats + (size_t)l * 128);
    float* tmp = h; h = hn; hn = tmp;
  }

  // ---- Final BN + ReLU + prediction + log_softmax (MFMA) ----
  k_pred_mfma<<<LBLK, 256, 0, stream>>>(
      h, stats + (size_t)(NL - 1) * 128,
      gamma + (size_t)(NL - 1) * DH, beta + (size_t)(NL - 1) * DH,
      W_pred, b_pred, out);
}